// Round 1
// baseline (986.219 us; speedup 1.0000x reference)
//
#include <hip/hip_runtime.h>
#include <math.h>

#define CH 512
#define CQ 64
#define HH 64
#define WW 64
#define PP (HH*WW)   // 4096
#define BB 8

// ---------------------------------------------------------------------------
// proj: Y[b, p, o] = sum_c W[o,c] * X[b,c,p] + bias[o]   (channel-last output)
// grid (P/128, M/64, B), block 256
// ---------------------------------------------------------------------------
__global__ __launch_bounds__(256) void proj_kernel(
    const float* __restrict__ X, const float* __restrict__ W,
    const float* __restrict__ bias, float* __restrict__ Y, int M)
{
  const int tid = threadIdx.x;
  const int b  = blockIdx.z;
  const int o0 = blockIdx.y * 64;
  const int p0 = blockIdx.x * 128;
  __shared__ float Xs[16][128];
  __shared__ float Ws[16][68];   // pad 68 keeps 16B alignment, spreads banks

  const int tx = tid & 15;       // o = o0 + 4*tx .. +3
  const int ty = tid >> 4;       // px = ty*8 + i
  float4 acc[8];
  float4 bv4 = *(const float4*)(bias + o0 + 4*tx);
  #pragma unroll
  for (int i = 0; i < 8; ++i) acc[i] = bv4;

  const float* Xb = X + ((size_t)b * CH) * PP + p0;
  for (int c0 = 0; c0 < CH; c0 += 16) {
    {
      int col4 = tid & 31;
      int r    = tid >> 5;
      #pragma unroll
      for (int pp = 0; pp < 2; ++pp) {
        int row = r + 8*pp;
        float4 v = *(const float4*)(Xb + (size_t)(c0 + row) * PP + 4*col4);
        *(float4*)&Xs[row][4*col4] = v;
      }
    }
    {
      int o = tid >> 2;
      int q = tid & 3;
      float4 wv = *(const float4*)(W + (size_t)(o0 + o) * CH + c0 + 4*q);
      Ws[4*q+0][o] = wv.x;
      Ws[4*q+1][o] = wv.y;
      Ws[4*q+2][o] = wv.z;
      Ws[4*q+3][o] = wv.w;
    }
    __syncthreads();
    #pragma unroll
    for (int kk = 0; kk < 16; ++kk) {
      float4 w4 = *(const float4*)&Ws[kk][4*tx];
      #pragma unroll
      for (int i = 0; i < 8; ++i) {
        float xv = Xs[kk][ty*8 + i];
        acc[i].x += xv * w4.x;
        acc[i].y += xv * w4.y;
        acc[i].z += xv * w4.z;
        acc[i].w += xv * w4.w;
      }
    }
    __syncthreads();
  }
  float* Yb = Y + ((size_t)b * PP + p0) * M + o0 + 4*tx;
  #pragma unroll
  for (int i = 0; i < 8; ++i) {
    *(float4*)(Yb + (size_t)(ty*8 + i) * M) = acc[i];
  }
}

// ---------------------------------------------------------------------------
// energyH: per (b,w) block: att[b,h,w,g] = (h<L && g<L) ? sum_{c<L} q.k : 0
//          with -inf on the diagonal g==h.  grid (W, B), block 256.
// q_t/k_t layout: (b, p=h*64+w, c) channel-last, c=64.
// ---------------------------------------------------------------------------
__global__ __launch_bounds__(256) void energyH_kernel(
    const float* __restrict__ qt, const float* __restrict__ kt,
    float* __restrict__ att, const int* __restrict__ len_p)
{
  const int tid = threadIdx.x;
  const int w = blockIdx.x, b = blockIdx.y;
  int L = *len_p; L = L < 0 ? 0 : (L > 64 ? 64 : L);
  __shared__ float Qs[64][68];
  __shared__ float Ks[64][68];
  {
    const int c = tid & 63, hg = tid >> 6;
    const float* qb = qt + ((size_t)b * PP + w) * CQ + c;
    const float* kb = kt + ((size_t)b * PP + w) * CQ + c;
    #pragma unroll
    for (int r = 0; r < 16; ++r) {
      int h = hg*16 + r;
      Qs[h][c] = qb[(size_t)h * WW * CQ];
      Ks[h][c] = kb[(size_t)h * WW * CQ];
    }
  }
  __syncthreads();
  const int g  = tid & 63;   // lane id within wave
  const int wg = tid >> 6;   // wave -> h group
  float kreg[64];
  #pragma unroll
  for (int c = 0; c < 64; ++c) kreg[c] = (c < L) ? Ks[g][c] : 0.0f;
  const bool gok = (g < L);
  float* ab = att + (((size_t)b * HH) * WW + w) * 128 + g;
  for (int r = 0; r < 16; ++r) {
    int h = wg*16 + r;
    float e = 0.0f;
    #pragma unroll
    for (int c4 = 0; c4 < 16; ++c4) {
      float4 q4 = *(const float4*)&Qs[h][4*c4];
      e += q4.x*kreg[4*c4+0] + q4.y*kreg[4*c4+1]
         + q4.z*kreg[4*c4+2] + q4.w*kreg[4*c4+3];
    }
    e = (gok && h < L) ? e : 0.0f;
    if (g == h) e = -INFINITY;
    ab[(size_t)h * WW * 128] = e;
  }
}

// ---------------------------------------------------------------------------
// energyW + softmax: per (b,h) block. eW[w,g] = (w<L && g<L) ? sum_{c<L} : 0
// then softmax over [eH(64) | eW(64)] per pixel.  grid (H, B), block 256.
// ---------------------------------------------------------------------------
__global__ __launch_bounds__(256) void energyW_softmax_kernel(
    const float* __restrict__ qt, const float* __restrict__ kt,
    float* __restrict__ att, const int* __restrict__ len_p)
{
  const int tid = threadIdx.x;
  const int h = blockIdx.x, b = blockIdx.y;
  int L = *len_p; L = L < 0 ? 0 : (L > 64 ? 64 : L);
  __shared__ float Qs[64][68];
  __shared__ float Ks[64][68];
  {
    const int c = tid & 63, wg2 = tid >> 6;
    const float* qb = qt + ((size_t)b * PP + (size_t)h * WW) * CQ + c;
    const float* kb = kt + ((size_t)b * PP + (size_t)h * WW) * CQ + c;
    #pragma unroll
    for (int r = 0; r < 16; ++r) {
      int w = wg2*16 + r;
      Qs[w][c] = qb[(size_t)w * CQ];
      Ks[w][c] = kb[(size_t)w * CQ];
    }
  }
  __syncthreads();
  const int g  = tid & 63;
  const int wg = tid >> 6;
  float kreg[64];
  #pragma unroll
  for (int c = 0; c < 64; ++c) kreg[c] = (c < L) ? Ks[g][c] : 0.0f;
  const bool gok = (g < L);
  float* ab = att + (((size_t)b * HH + h) * WW) * 128 + g;
  for (int r = 0; r < 16; ++r) {
    int w = wg*16 + r;
    float e = 0.0f;
    #pragma unroll
    for (int c4 = 0; c4 < 16; ++c4) {
      float4 q4 = *(const float4*)&Qs[w][4*c4];
      e += q4.x*kreg[4*c4+0] + q4.y*kreg[4*c4+1]
         + q4.z*kreg[4*c4+2] + q4.w*kreg[4*c4+3];
    }
    e = (gok && w < L) ? e : 0.0f;
    float eh = ab[(size_t)w * 128];        // H-half energy (may be -inf on diag)
    float m = fmaxf(e, eh);
    #pragma unroll
    for (int d = 32; d > 0; d >>= 1) m = fmaxf(m, __shfl_xor(m, d, 64));
    float pe = __expf(e  - m);
    float ph = __expf(eh - m);
    float s = pe + ph;
    #pragma unroll
    for (int d = 32; d > 0; d >>= 1) s += __shfl_xor(s, d, 64);
    float inv = 1.0f / s;
    ab[(size_t)w * 128]      = ph * inv;   // attH
    ab[(size_t)w * 128 + 64] = pe * inv;   // attW
  }
}

// ---------------------------------------------------------------------------
// outH: per (b,w): out_raw[b,c,h,w] = sum_j att[b,h,w,j] * v_t[b, j*64+w, c]
// (raw, no gamma). grid (W, B), block 256. Strided scatter write (accepted).
// ---------------------------------------------------------------------------
__global__ __launch_bounds__(256) void outH_kernel(
    const float* __restrict__ att, const float* __restrict__ vt,
    float* __restrict__ out)
{
  const int tid = threadIdx.x;
  const int w = blockIdx.x, b = blockIdx.y;
  __shared__ float As[64][68];
  __shared__ float Bs[16][132];
  {
    int jf = tid & 15;
    int h0 = tid >> 4;
    const float* ab = att + (((size_t)b * HH) * WW + w) * 128;
    #pragma unroll
    for (int pp = 0; pp < 4; ++pp) {
      int hh2 = h0 + 16*pp;
      float4 v = *(const float4*)(ab + (size_t)hh2 * WW * 128 + 4*jf);
      *(float4*)&As[hh2][4*jf] = v;
    }
  }
  __syncthreads();
  const int tx = tid & 31;   // c' = 4*tx
  const int ty = tid >> 5;   // h = 8*ty + i
  const float* vb = vt + ((size_t)b * PP + w) * CH;
  for (int ct = 0; ct < 4; ++ct) {
    const int c0 = ct * 128;
    float4 acc[8];
    #pragma unroll
    for (int i = 0; i < 8; ++i) acc[i] = make_float4(0.f,0.f,0.f,0.f);
    for (int jt = 0; jt < 4; ++jt) {
      {
        int c4 = tid & 31;
        int jj = tid >> 5;
        #pragma unroll
        for (int pp = 0; pp < 2; ++pp) {
          int j = jj + 8*pp;
          float4 v = *(const float4*)(vb + (size_t)(jt*16 + j) * WW * CH + c0 + 4*c4);
          *(float4*)&Bs[j][4*c4] = v;
        }
      }
      __syncthreads();
      #pragma unroll
      for (int kb = 0; kb < 4; ++kb) {
        float4 a4[8];
        #pragma unroll
        for (int i = 0; i < 8; ++i)
          a4[i] = *(const float4*)&As[8*ty+i][jt*16 + 4*kb];
        #pragma unroll
        for (int kk = 0; kk < 4; ++kk) {
          float4 b4 = *(const float4*)&Bs[4*kb+kk][4*tx];
          #pragma unroll
          for (int i = 0; i < 8; ++i) {
            float a = (kk==0)?a4[i].x:(kk==1)?a4[i].y:(kk==2)?a4[i].z:a4[i].w;
            acc[i].x += a * b4.x; acc[i].y += a * b4.y;
            acc[i].z += a * b4.z; acc[i].w += a * b4.w;
          }
        }
      }
      __syncthreads();
    }
    float* ob = out + ((size_t)b * CH + c0 + 4*tx) * PP + w;
    #pragma unroll
    for (int i = 0; i < 8; ++i) {
      int h = 8*ty + i;
      ob[(size_t)0*PP + h*WW] = acc[i].x;
      ob[(size_t)1*PP + h*WW] = acc[i].y;
      ob[(size_t)2*PP + h*WW] = acc[i].z;
      ob[(size_t)3*PP + h*WW] = acc[i].w;
    }
  }
}

// ---------------------------------------------------------------------------
// outW + final: per (b,h): out = gamma*(outW + outH_prev) + x1
// grid (H, B), block 256. Coalesced RMW via LDS transpose epilogue.
// ---------------------------------------------------------------------------
__global__ __launch_bounds__(256) void outW_final_kernel(
    const float* __restrict__ att, const float* __restrict__ vt,
    const float* __restrict__ x1, const float* __restrict__ gamma_p,
    float* __restrict__ out)
{
  const int tid = threadIdx.x;
  const int h = blockIdx.x, b = blockIdx.y;
  const float gamma = *gamma_p;
  __shared__ float As[64][68];
  __shared__ float Pool[64][132];   // Bs (rows 0..15) and Ts (all rows) share
  {
    int jf = tid & 15;
    int w0 = tid >> 4;
    const float* ab = att + (((size_t)b * HH + h) * WW) * 128 + 64;
    #pragma unroll
    for (int pp = 0; pp < 4; ++pp) {
      int ww2 = w0 + 16*pp;
      float4 v = *(const float4*)(ab + (size_t)ww2 * 128 + 4*jf);
      *(float4*)&As[ww2][4*jf] = v;
    }
  }
  __syncthreads();
  const int tx = tid & 31;
  const int ty = tid >> 5;
  const float* vb = vt + ((size_t)b * PP + (size_t)h * WW) * CH;
  for (int ct = 0; ct < 4; ++ct) {
    const int c0 = ct * 128;
    float4 acc[8];
    #pragma unroll
    for (int i = 0; i < 8; ++i) acc[i] = make_float4(0.f,0.f,0.f,0.f);
    for (int jt = 0; jt < 4; ++jt) {
      {
        int c4 = tid & 31;
        int jj = tid >> 5;
        #pragma unroll
        for (int pp = 0; pp < 2; ++pp) {
          int j = jj + 8*pp;
          float4 v = *(const float4*)(vb + (size_t)(jt*16 + j) * CH + c0 + 4*c4);
          *(float4*)&Pool[j][4*c4] = v;
        }
      }
      __syncthreads();
      #pragma unroll
      for (int kb = 0; kb < 4; ++kb) {
        float4 a4[8];
        #pragma unroll
        for (int i = 0; i < 8; ++i)
          a4[i] = *(const float4*)&As[8*ty+i][jt*16 + 4*kb];
        #pragma unroll
        for (int kk = 0; kk < 4; ++kk) {
          float4 b4 = *(const float4*)&Pool[4*kb+kk][4*tx];
          #pragma unroll
          for (int i = 0; i < 8; ++i) {
            float a = (kk==0)?a4[i].x:(kk==1)?a4[i].y:(kk==2)?a4[i].z:a4[i].w;
            acc[i].x += a * b4.x; acc[i].y += a * b4.y;
            acc[i].z += a * b4.z; acc[i].w += a * b4.w;
          }
        }
      }
      __syncthreads();
    }
    // transpose tile into LDS so the global phase has lanes along w
    #pragma unroll
    for (int i = 0; i < 8; ++i)
      *(float4*)&Pool[8*ty + i][4*tx] = acc[i];
    __syncthreads();
    {
      int wl = tid & 63;
      int cg = tid >> 6;
      const float* x1b = x1 + ((size_t)b * CH + c0) * PP + (size_t)h * WW + wl;
      float*       ob  = out + ((size_t)b * CH + c0) * PP + (size_t)h * WW + wl;
      #pragma unroll
      for (int r = 0; r < 32; ++r) {
        int ci = cg*32 + r;
        float oh  = ob[(size_t)ci * PP];             // raw outH from outH_kernel
        float val = gamma * (Pool[wl][ci] + oh) + x1b[(size_t)ci * PP];
        ob[(size_t)ci * PP] = val;
      }
    }
    __syncthreads();   // Pool reused as Bs next ct
  }
}

// ---------------------------------------------------------------------------
extern "C" void kernel_launch(void* const* d_in, const int* in_sizes, int n_in,
                              void* d_out, int out_size, void* d_ws, size_t ws_size,
                              hipStream_t stream)
{
  const float* x1 = (const float*)d_in[0];
  const float* x2 = (const float*)d_in[1];
  const float* x3 = (const float*)d_in[2];
  const float* Wq = (const float*)d_in[3];
  const float* bq = (const float*)d_in[4];
  const float* Wk = (const float*)d_in[5];
  const float* bk = (const float*)d_in[6];
  const float* Wv = (const float*)d_in[7];
  const float* bv = (const float*)d_in[8];
  const float* gamma = (const float*)d_in[9];
  const int*   len   = (const int*)d_in[10];
  float* out = (float*)d_out;

  // workspace layout (96 MiB total):
  float* q_t = (float*)d_ws;                       // (B, P, 64)
  float* k_t = q_t + (size_t)BB * PP * CQ;         // (B, P, 64)
  float* v_t = k_t + (size_t)BB * PP * CQ;         // (B, P, 512)
  float* att = v_t + (size_t)BB * PP * CH;         // (B, H, W, 128)

  dim3 blk(256);
  proj_kernel<<<dim3(PP/128, CQ/64, BB), blk, 0, stream>>>(x1, Wq, bq, q_t, CQ);
  proj_kernel<<<dim3(PP/128, CQ/64, BB), blk, 0, stream>>>(x2, Wk, bk, k_t, CQ);
  proj_kernel<<<dim3(PP/128, CH/64, BB), blk, 0, stream>>>(x3, Wv, bv, v_t, CH);
  energyH_kernel<<<dim3(WW, BB), blk, 0, stream>>>(q_t, k_t, att, len);
  energyW_softmax_kernel<<<dim3(HH, BB), blk, 0, stream>>>(q_t, k_t, att, len);
  outH_kernel<<<dim3(WW, BB), blk, 0, stream>>>(att, v_t, out);
  outW_final_kernel<<<dim3(HH, BB), blk, 0, stream>>>(att, v_t, x1, gamma, out);
}

// Round 2
// 451.024 us; speedup vs baseline: 2.1866x; 2.1866x over previous
//
#include <hip/hip_runtime.h>
#include <math.h>

#define CH 512
#define CQ 64
#define HH 64
#define WW 64
#define PP (HH*WW)   // 4096
#define BB 8

typedef __bf16 bf16x8 __attribute__((ext_vector_type(8)));
typedef float  f32x4  __attribute__((ext_vector_type(4)));

// ---------------------------------------------------------------------------
// proj_mfma: Y[m, o] = sum_c X[b, c, p] * W[o, c] + bias[o],  m = b*4096 + p
// bf16 MFMA (16x16x32), reg-staged with on-the-fly f32->bf16 conversion.
// SPLIT=true uses hi+lo bf16 decomposition (3 MFMAs) for ~f32 accuracy.
// Template: wave grid 2x2, wave tile (FM*16) x (FN*16); BM=32*FM, BN=32*FN.
// grid (32768/BM, Nout/BN), block 256.
// ---------------------------------------------------------------------------
template<int FM, int FN, bool SPLIT>
__global__ __launch_bounds__(256) void proj_mfma_kernel(
    const float* __restrict__ X, const float* __restrict__ W,
    const float* __restrict__ bias, float* __restrict__ Y, int Nout)
{
  constexpr int BM = 32 * FM;
  constexpr int BN = 32 * FN;
  constexpr int NS = SPLIT ? 2 : 1;
  __shared__ __align__(16) __bf16 As[NS][BM][40];
  __shared__ __align__(16) __bf16 Bs[NS][BN][40];

  const int tid = threadIdx.x;
  const int mblk = blockIdx.x * BM;         // global m
  const int nblk = blockIdx.y * BN;
  const int b     = mblk >> 12;             // batch (BM divides 4096)
  const int pbase = mblk & 4095;
  const float* Xb = X + (size_t)b * CH * PP;

  const int l  = tid & 63;
  const int wv = tid >> 6;
  const int wr = wv >> 1, wc = wv & 1;
  const int lm = l & 15, lk = l >> 4;

  f32x4 acc[FM][FN];
  #pragma unroll
  for (int j = 0; j < FN; ++j) {
    float bvj = bias[nblk + wc*FN*16 + j*16 + lm];
    #pragma unroll
    for (int i = 0; i < FM; ++i) {
      acc[i][j][0] = bvj; acc[i][j][1] = bvj;
      acc[i][j][2] = bvj; acc[i][j][3] = bvj;
    }
  }

  for (int c0 = 0; c0 < CH; c0 += 32) {
    // ---- stage A (from X, k-major source -> [m][k] tile, transposed in reg)
    #pragma unroll
    for (int g = tid; g < BM*4; g += 256) {
      int m  = g % BM;
      int k0 = (g / BM) * 8;
      float xs[8];
      #pragma unroll
      for (int jj = 0; jj < 8; ++jj)
        xs[jj] = Xb[(size_t)(c0 + k0 + jj) * PP + pbase + m];
      bf16x8 hv, lv;
      #pragma unroll
      for (int jj = 0; jj < 8; ++jj) {
        __bf16 hh = (__bf16)xs[jj];
        hv[jj] = hh;
        if (SPLIT) lv[jj] = (__bf16)(xs[jj] - (float)hh);
      }
      *(bf16x8*)&As[0][m][k0] = hv;
      if (SPLIT) *(bf16x8*)&As[1][m][k0] = lv;
    }
    // ---- stage B (from W, k contiguous -> [n][k] tile)
    #pragma unroll
    for (int g = tid; g < BN*4; g += 256) {
      int n  = g >> 2;
      int k0 = (g & 3) * 8;
      const float* src = W + (size_t)(nblk + n) * CH + c0 + k0;
      float4 f0 = *(const float4*)src;
      float4 f1 = *(const float4*)(src + 4);
      float xs[8] = {f0.x,f0.y,f0.z,f0.w,f1.x,f1.y,f1.z,f1.w};
      bf16x8 hv, lv;
      #pragma unroll
      for (int jj = 0; jj < 8; ++jj) {
        __bf16 hh = (__bf16)xs[jj];
        hv[jj] = hh;
        if (SPLIT) lv[jj] = (__bf16)(xs[jj] - (float)hh);
      }
      *(bf16x8*)&Bs[0][n][k0] = hv;
      if (SPLIT) *(bf16x8*)&Bs[1][n][k0] = lv;
    }
    __syncthreads();
    // ---- fragments + MFMA
    bf16x8 af[NS][FM], bfr[NS][FN];
    #pragma unroll
    for (int s = 0; s < NS; ++s) {
      #pragma unroll
      for (int i = 0; i < FM; ++i)
        af[s][i] = *(const bf16x8*)&As[s][wr*FM*16 + i*16 + lm][lk*8];
      #pragma unroll
      for (int j = 0; j < FN; ++j)
        bfr[s][j] = *(const bf16x8*)&Bs[s][wc*FN*16 + j*16 + lm][lk*8];
    }
    #pragma unroll
    for (int i = 0; i < FM; ++i) {
      #pragma unroll
      for (int j = 0; j < FN; ++j) {
        acc[i][j] = __builtin_amdgcn_mfma_f32_16x16x32_bf16(
            af[0][i], bfr[0][j], acc[i][j], 0, 0, 0);
        if (SPLIT) {
          acc[i][j] = __builtin_amdgcn_mfma_f32_16x16x32_bf16(
              af[0][i], bfr[1][j], acc[i][j], 0, 0, 0);
          acc[i][j] = __builtin_amdgcn_mfma_f32_16x16x32_bf16(
              af[1][i], bfr[0][j], acc[i][j], 0, 0, 0);
        }
      }
    }
    __syncthreads();
  }
  // ---- epilogue: C/D layout col=lane&15, row=(lane>>4)*4+r
  #pragma unroll
  for (int i = 0; i < FM; ++i) {
    #pragma unroll
    for (int j = 0; j < FN; ++j) {
      #pragma unroll
      for (int r = 0; r < 4; ++r) {
        int mg = mblk + wr*FM*16 + i*16 + lk*4 + r;
        int ng = nblk + wc*FN*16 + j*16 + lm;
        Y[(size_t)mg * Nout + ng] = acc[i][j][r];
      }
    }
  }
}

// ---------------------------------------------------------------------------
// energyH: per (b,w) block: att[b,h,w,g] = (h<L && g<L) ? sum_{c<L} q.k : 0
//          with -inf on the diagonal g==h.  grid (W, B), block 256.
// ---------------------------------------------------------------------------
__global__ __launch_bounds__(256) void energyH_kernel(
    const float* __restrict__ qt, const float* __restrict__ kt,
    float* __restrict__ att, const int* __restrict__ len_p)
{
  const int tid = threadIdx.x;
  const int w = blockIdx.x, b = blockIdx.y;
  int L = *len_p; L = L < 0 ? 0 : (L > 64 ? 64 : L);
  __shared__ float Qs[64][68];
  __shared__ float Ks[64][68];
  {
    const int c = tid & 63, hg = tid >> 6;
    const float* qb = qt + ((size_t)b * PP + w) * CQ + c;
    const float* kb = kt + ((size_t)b * PP + w) * CQ + c;
    #pragma unroll
    for (int r = 0; r < 16; ++r) {
      int h = hg*16 + r;
      Qs[h][c] = qb[(size_t)h * WW * CQ];
      Ks[h][c] = kb[(size_t)h * WW * CQ];
    }
  }
  __syncthreads();
  const int g  = tid & 63;
  const int wg = tid >> 6;
  float kreg[64];
  #pragma unroll
  for (int c = 0; c < 64; ++c) kreg[c] = (c < L) ? Ks[g][c] : 0.0f;
  const bool gok = (g < L);
  float* ab = att + (((size_t)b * HH) * WW + w) * 128 + g;
  for (int r = 0; r < 16; ++r) {
    int h = wg*16 + r;
    float e = 0.0f;
    #pragma unroll
    for (int c4 = 0; c4 < 16; ++c4) {
      float4 q4 = *(const float4*)&Qs[h][4*c4];
      e += q4.x*kreg[4*c4+0] + q4.y*kreg[4*c4+1]
         + q4.z*kreg[4*c4+2] + q4.w*kreg[4*c4+3];
    }
    e = (gok && h < L) ? e : 0.0f;
    if (g == h) e = -INFINITY;
    ab[(size_t)h * WW * 128] = e;
  }
}

// ---------------------------------------------------------------------------
// energyW + softmax over [eH | eW].  grid (H, B), block 256.
// ---------------------------------------------------------------------------
__global__ __launch_bounds__(256) void energyW_softmax_kernel(
    const float* __restrict__ qt, const float* __restrict__ kt,
    float* __restrict__ att, const int* __restrict__ len_p)
{
  const int tid = threadIdx.x;
  const int h = blockIdx.x, b = blockIdx.y;
  int L = *len_p; L = L < 0 ? 0 : (L > 64 ? 64 : L);
  __shared__ float Qs[64][68];
  __shared__ float Ks[64][68];
  {
    const int c = tid & 63, wg2 = tid >> 6;
    const float* qb = qt + ((size_t)b * PP + (size_t)h * WW) * CQ + c;
    const float* kb = kt + ((size_t)b * PP + (size_t)h * WW) * CQ + c;
    #pragma unroll
    for (int r = 0; r < 16; ++r) {
      int w = wg2*16 + r;
      Qs[w][c] = qb[(size_t)w * CQ];
      Ks[w][c] = kb[(size_t)w * CQ];
    }
  }
  __syncthreads();
  const int g  = tid & 63;
  const int wg = tid >> 6;
  float kreg[64];
  #pragma unroll
  for (int c = 0; c < 64; ++c) kreg[c] = (c < L) ? Ks[g][c] : 0.0f;
  const bool gok = (g < L);
  float* ab = att + (((size_t)b * HH + h) * WW) * 128 + g;
  for (int r = 0; r < 16; ++r) {
    int w = wg*16 + r;
    float e = 0.0f;
    #pragma unroll
    for (int c4 = 0; c4 < 16; ++c4) {
      float4 q4 = *(const float4*)&Qs[w][4*c4];
      e += q4.x*kreg[4*c4+0] + q4.y*kreg[4*c4+1]
         + q4.z*kreg[4*c4+2] + q4.w*kreg[4*c4+3];
    }
    e = (gok && w < L) ? e : 0.0f;
    float eh = ab[(size_t)w * 128];
    float m = fmaxf(e, eh);
    #pragma unroll
    for (int d = 32; d > 0; d >>= 1) m = fmaxf(m, __shfl_xor(m, d, 64));
    float pe = __expf(e  - m);
    float ph = __expf(eh - m);
    float s = pe + ph;
    #pragma unroll
    for (int d = 32; d > 0; d >>= 1) s += __shfl_xor(s, d, 64);
    float inv = 1.0f / s;
    ab[(size_t)w * 128]      = ph * inv;   // attH
    ab[(size_t)w * 128 + 64] = pe * inv;   // attW
  }
}

// ---------------------------------------------------------------------------
// outH: per (b,w): out_raw[b,c,h,w] = sum_j att[b,h,w,j] * v_t[b, j*64+w, c]
// ---------------------------------------------------------------------------
__global__ __launch_bounds__(256) void outH_kernel(
    const float* __restrict__ att, const float* __restrict__ vt,
    float* __restrict__ out)
{
  const int tid = threadIdx.x;
  const int w = blockIdx.x, b = blockIdx.y;
  __shared__ float As[64][68];
  __shared__ float Bs[16][132];
  {
    int jf = tid & 15;
    int h0 = tid >> 4;
    const float* ab = att + (((size_t)b * HH) * WW + w) * 128;
    #pragma unroll
    for (int pp = 0; pp < 4; ++pp) {
      int hh2 = h0 + 16*pp;
      float4 v = *(const float4*)(ab + (size_t)hh2 * WW * 128 + 4*jf);
      *(float4*)&As[hh2][4*jf] = v;
    }
  }
  __syncthreads();
  const int tx = tid & 31;
  const int ty = tid >> 5;
  const float* vb = vt + ((size_t)b * PP + w) * CH;
  for (int ct = 0; ct < 4; ++ct) {
    const int c0 = ct * 128;
    float4 acc[8];
    #pragma unroll
    for (int i = 0; i < 8; ++i) acc[i] = make_float4(0.f,0.f,0.f,0.f);
    for (int jt = 0; jt < 4; ++jt) {
      {
        int c4 = tid & 31;
        int jj = tid >> 5;
        #pragma unroll
        for (int pp = 0; pp < 2; ++pp) {
          int j = jj + 8*pp;
          float4 v = *(const float4*)(vb + (size_t)(jt*16 + j) * WW * CH + c0 + 4*c4);
          *(float4*)&Bs[j][4*c4] = v;
        }
      }
      __syncthreads();
      #pragma unroll
      for (int kb = 0; kb < 4; ++kb) {
        float4 a4[8];
        #pragma unroll
        for (int i = 0; i < 8; ++i)
          a4[i] = *(const float4*)&As[8*ty+i][jt*16 + 4*kb];
        #pragma unroll
        for (int kk = 0; kk < 4; ++kk) {
          float4 b4 = *(const float4*)&Bs[4*kb+kk][4*tx];
          #pragma unroll
          for (int i = 0; i < 8; ++i) {
            float a = (kk==0)?a4[i].x:(kk==1)?a4[i].y:(kk==2)?a4[i].z:a4[i].w;
            acc[i].x += a * b4.x; acc[i].y += a * b4.y;
            acc[i].z += a * b4.z; acc[i].w += a * b4.w;
          }
        }
      }
      __syncthreads();
    }
    float* ob = out + ((size_t)b * CH + c0 + 4*tx) * PP + w;
    #pragma unroll
    for (int i = 0; i < 8; ++i) {
      int h = 8*ty + i;
      ob[(size_t)0*PP + h*WW] = acc[i].x;
      ob[(size_t)1*PP + h*WW] = acc[i].y;
      ob[(size_t)2*PP + h*WW] = acc[i].z;
      ob[(size_t)3*PP + h*WW] = acc[i].w;
    }
  }
}

// ---------------------------------------------------------------------------
// outW + final: per (b,h): out = gamma*(outW + outH_prev) + x1
// ---------------------------------------------------------------------------
__global__ __launch_bounds__(256) void outW_final_kernel(
    const float* __restrict__ att, const float* __restrict__ vt,
    const float* __restrict__ x1, const float* __restrict__ gamma_p,
    float* __restrict__ out)
{
  const int tid = threadIdx.x;
  const int h = blockIdx.x, b = blockIdx.y;
  const float gamma = *gamma_p;
  __shared__ float As[64][68];
  __shared__ float Pool[64][132];
  {
    int jf = tid & 15;
    int w0 = tid >> 4;
    const float* ab = att + (((size_t)b * HH + h) * WW) * 128 + 64;
    #pragma unroll
    for (int pp = 0; pp < 4; ++pp) {
      int ww2 = w0 + 16*pp;
      float4 v = *(const float4*)(ab + (size_t)ww2 * 128 + 4*jf);
      *(float4*)&As[ww2][4*jf] = v;
    }
  }
  __syncthreads();
  const int tx = tid & 31;
  const int ty = tid >> 5;
  const float* vb = vt + ((size_t)b * PP + (size_t)h * WW) * CH;
  for (int ct = 0; ct < 4; ++ct) {
    const int c0 = ct * 128;
    float4 acc[8];
    #pragma unroll
    for (int i = 0; i < 8; ++i) acc[i] = make_float4(0.f,0.f,0.f,0.f);
    for (int jt = 0; jt < 4; ++jt) {
      {
        int c4 = tid & 31;
        int jj = tid >> 5;
        #pragma unroll
        for (int pp = 0; pp < 2; ++pp) {
          int j = jj + 8*pp;
          float4 v = *(const float4*)(vb + (size_t)(jt*16 + j) * CH + c0 + 4*c4);
          *(float4*)&Pool[j][4*c4] = v;
        }
      }
      __syncthreads();
      #pragma unroll
      for (int kb = 0; kb < 4; ++kb) {
        float4 a4[8];
        #pragma unroll
        for (int i = 0; i < 8; ++i)
          a4[i] = *(const float4*)&As[8*ty+i][jt*16 + 4*kb];
        #pragma unroll
        for (int kk = 0; kk < 4; ++kk) {
          float4 b4 = *(const float4*)&Pool[4*kb+kk][4*tx];
          #pragma unroll
          for (int i = 0; i < 8; ++i) {
            float a = (kk==0)?a4[i].x:(kk==1)?a4[i].y:(kk==2)?a4[i].z:a4[i].w;
            acc[i].x += a * b4.x; acc[i].y += a * b4.y;
            acc[i].z += a * b4.z; acc[i].w += a * b4.w;
          }
        }
      }
      __syncthreads();
    }
    #pragma unroll
    for (int i = 0; i < 8; ++i)
      *(float4*)&Pool[8*ty + i][4*tx] = acc[i];
    __syncthreads();
    {
      int wl = tid & 63;
      int cg = tid >> 6;
      const float* x1b = x1 + ((size_t)b * CH + c0) * PP + (size_t)h * WW + wl;
      float*       ob  = out + ((size_t)b * CH + c0) * PP + (size_t)h * WW + wl;
      #pragma unroll
      for (int r = 0; r < 32; ++r) {
        int ci = cg*32 + r;
        float oh  = ob[(size_t)ci * PP];
        float val = gamma * (Pool[wl][ci] + oh) + x1b[(size_t)ci * PP];
        ob[(size_t)ci * PP] = val;
      }
    }
    __syncthreads();
  }
}

// ---------------------------------------------------------------------------
extern "C" void kernel_launch(void* const* d_in, const int* in_sizes, int n_in,
                              void* d_out, int out_size, void* d_ws, size_t ws_size,
                              hipStream_t stream)
{
  const float* x1 = (const float*)d_in[0];
  const float* x2 = (const float*)d_in[1];
  const float* x3 = (const float*)d_in[2];
  const float* Wq = (const float*)d_in[3];
  const float* bq = (const float*)d_in[4];
  const float* Wk = (const float*)d_in[5];
  const float* bk = (const float*)d_in[6];
  const float* Wv = (const float*)d_in[7];
  const float* bv = (const float*)d_in[8];
  const float* gamma = (const float*)d_in[9];
  const int*   len   = (const int*)d_in[10];
  float* out = (float*)d_out;

  float* q_t = (float*)d_ws;                       // (B, P, 64)
  float* k_t = q_t + (size_t)BB * PP * CQ;         // (B, P, 64)
  float* v_t = k_t + (size_t)BB * PP * CQ;         // (B, P, 512)
  float* att = v_t + (size_t)BB * PP * CH;         // (B, H, W, 128)

  dim3 blk(256);
  // v: 128x128 tile, single bf16; q/k: 64x64 tile, split-bf16 (hi+lo)
  proj_mfma_kernel<4,4,false><<<dim3(BB*PP/128, CH/128), blk, 0, stream>>>(x3, Wv, bv, v_t, CH);
  proj_mfma_kernel<2,2,true ><<<dim3(BB*PP/64,  1),      blk, 0, stream>>>(x1, Wq, bq, q_t, CQ);
  proj_mfma_kernel<2,2,true ><<<dim3(BB*PP/64,  1),      blk, 0, stream>>>(x2, Wk, bk, k_t, CQ);
  energyH_kernel<<<dim3(WW, BB), blk, 0, stream>>>(q_t, k_t, att, len);
  energyW_softmax_kernel<<<dim3(HH, BB), blk, 0, stream>>>(q_t, k_t, att, len);
  outH_kernel<<<dim3(WW, BB), blk, 0, stream>>>(att, v_t, out);
  outW_final_kernel<<<dim3(HH, BB), blk, 0, stream>>>(att, v_t, x1, gamma, out);
}

// Round 3
// 244.484 us; speedup vs baseline: 4.0339x; 1.8448x over previous
//
#include <hip/hip_runtime.h>
#include <math.h>

#define CH 512
#define CQ 64
#define HH 64
#define WW 64
#define PP (HH*WW)   // 4096
#define BB 8

typedef __bf16 bf16x8 __attribute__((ext_vector_type(8)));
typedef __bf16 bf16x4 __attribute__((ext_vector_type(4)));
typedef float  f32x4  __attribute__((ext_vector_type(4)));

// ---------------------------------------------------------------------------
// proj_mfma: Y[m, o] = sum_c X[b, c, p] * W[o, c] + bias[o],  m = b*4096 + p
// bf16 MFMA (16x16x32), reg-staged with on-the-fly f32->bf16 conversion.
// SPLIT=true uses hi+lo bf16 decomposition (3 MFMAs) for ~f32 accuracy.
// OutT: float (q,k) or __bf16 (v).
// ---------------------------------------------------------------------------
template<int FM, int FN, bool SPLIT, typename OutT>
__global__ __launch_bounds__(256) void proj_mfma_kernel(
    const float* __restrict__ X, const float* __restrict__ W,
    const float* __restrict__ bias, OutT* __restrict__ Y, int Nout)
{
  constexpr int BM = 32 * FM;
  constexpr int BN = 32 * FN;
  constexpr int NS = SPLIT ? 2 : 1;
  __shared__ __align__(16) __bf16 As[NS][BM][40];
  __shared__ __align__(16) __bf16 Bs[NS][BN][40];

  const int tid = threadIdx.x;
  const int mblk = blockIdx.x * BM;         // global m
  const int nblk = blockIdx.y * BN;
  const int b     = mblk >> 12;             // batch (BM divides 4096)
  const int pbase = mblk & 4095;
  const float* Xb = X + (size_t)b * CH * PP;

  const int l  = tid & 63;
  const int wv = tid >> 6;
  const int wr = wv >> 1, wc = wv & 1;
  const int lm = l & 15, lk = l >> 4;

  f32x4 acc[FM][FN];
  #pragma unroll
  for (int j = 0; j < FN; ++j) {
    float bvj = bias[nblk + wc*FN*16 + j*16 + lm];
    #pragma unroll
    for (int i = 0; i < FM; ++i) {
      acc[i][j][0] = bvj; acc[i][j][1] = bvj;
      acc[i][j][2] = bvj; acc[i][j][3] = bvj;
    }
  }

  for (int c0 = 0; c0 < CH; c0 += 32) {
    // ---- stage A (from X, k-major source -> [m][k] tile, transposed in reg)
    #pragma unroll
    for (int g = tid; g < BM*4; g += 256) {
      int m  = g % BM;
      int k0 = (g / BM) * 8;
      float xs[8];
      #pragma unroll
      for (int jj = 0; jj < 8; ++jj)
        xs[jj] = Xb[(size_t)(c0 + k0 + jj) * PP + pbase + m];
      bf16x8 hv, lv;
      #pragma unroll
      for (int jj = 0; jj < 8; ++jj) {
        __bf16 hh = (__bf16)xs[jj];
        hv[jj] = hh;
        if (SPLIT) lv[jj] = (__bf16)(xs[jj] - (float)hh);
      }
      *(bf16x8*)&As[0][m][k0] = hv;
      if (SPLIT) *(bf16x8*)&As[1][m][k0] = lv;
    }
    // ---- stage B (from W, k contiguous -> [n][k] tile)
    #pragma unroll
    for (int g = tid; g < BN*4; g += 256) {
      int n  = g >> 2;
      int k0 = (g & 3) * 8;
      const float* src = W + (size_t)(nblk + n) * CH + c0 + k0;
      float4 f0 = *(const float4*)src;
      float4 f1 = *(const float4*)(src + 4);
      float xs[8] = {f0.x,f0.y,f0.z,f0.w,f1.x,f1.y,f1.z,f1.w};
      bf16x8 hv, lv;
      #pragma unroll
      for (int jj = 0; jj < 8; ++jj) {
        __bf16 hh = (__bf16)xs[jj];
        hv[jj] = hh;
        if (SPLIT) lv[jj] = (__bf16)(xs[jj] - (float)hh);
      }
      *(bf16x8*)&Bs[0][n][k0] = hv;
      if (SPLIT) *(bf16x8*)&Bs[1][n][k0] = lv;
    }
    __syncthreads();
    // ---- fragments + MFMA
    bf16x8 af[NS][FM], bfr[NS][FN];
    #pragma unroll
    for (int s = 0; s < NS; ++s) {
      #pragma unroll
      for (int i = 0; i < FM; ++i)
        af[s][i] = *(const bf16x8*)&As[s][wr*FM*16 + i*16 + lm][lk*8];
      #pragma unroll
      for (int j = 0; j < FN; ++j)
        bfr[s][j] = *(const bf16x8*)&Bs[s][wc*FN*16 + j*16 + lm][lk*8];
    }
    #pragma unroll
    for (int i = 0; i < FM; ++i) {
      #pragma unroll
      for (int j = 0; j < FN; ++j) {
        acc[i][j] = __builtin_amdgcn_mfma_f32_16x16x32_bf16(
            af[0][i], bfr[0][j], acc[i][j], 0, 0, 0);
        if (SPLIT) {
          acc[i][j] = __builtin_amdgcn_mfma_f32_16x16x32_bf16(
              af[0][i], bfr[1][j], acc[i][j], 0, 0, 0);
          acc[i][j] = __builtin_amdgcn_mfma_f32_16x16x32_bf16(
              af[1][i], bfr[0][j], acc[i][j], 0, 0, 0);
        }
      }
    }
    __syncthreads();
  }
  // ---- epilogue: C/D layout col=lane&15, row=(lane>>4)*4+r
  #pragma unroll
  for (int i = 0; i < FM; ++i) {
    #pragma unroll
    for (int j = 0; j < FN; ++j) {
      #pragma unroll
      for (int r = 0; r < 4; ++r) {
        int mg = mblk + wr*FM*16 + i*16 + lk*4 + r;
        int ng = nblk + wc*FN*16 + j*16 + lm;
        Y[(size_t)mg * Nout + ng] = (OutT)acc[i][j][r];
      }
    }
  }
}

// ---------------------------------------------------------------------------
// energyH: per (b,w) block: att[b,h,w,g] = (h<L && g<L) ? sum_{c<L} q.k : 0
//          with -inf on the diagonal g==h.  grid (W, B), block 256.
// ---------------------------------------------------------------------------
__global__ __launch_bounds__(256) void energyH_kernel(
    const float* __restrict__ qt, const float* __restrict__ kt,
    float* __restrict__ att, const int* __restrict__ len_p)
{
  const int tid = threadIdx.x;
  const int w = blockIdx.x, b = blockIdx.y;
  int L = *len_p; L = L < 0 ? 0 : (L > 64 ? 64 : L);
  __shared__ float Qs[64][68];
  __shared__ float Ks[64][68];
  {
    const int c = tid & 63, hg = tid >> 6;
    const float* qb = qt + ((size_t)b * PP + w) * CQ + c;
    const float* kb = kt + ((size_t)b * PP + w) * CQ + c;
    #pragma unroll
    for (int r = 0; r < 16; ++r) {
      int h = hg*16 + r;
      Qs[h][c] = qb[(size_t)h * WW * CQ];
      Ks[h][c] = kb[(size_t)h * WW * CQ];
    }
  }
  __syncthreads();
  const int g  = tid & 63;
  const int wg = tid >> 6;
  float kreg[64];
  #pragma unroll
  for (int c = 0; c < 64; ++c) kreg[c] = (c < L) ? Ks[g][c] : 0.0f;
  const bool gok = (g < L);
  float* ab = att + (((size_t)b * HH) * WW + w) * 128 + g;
  for (int r = 0; r < 16; ++r) {
    int h = wg*16 + r;
    float e = 0.0f;
    #pragma unroll
    for (int c4 = 0; c4 < 16; ++c4) {
      float4 q4 = *(const float4*)&Qs[h][4*c4];
      e += q4.x*kreg[4*c4+0] + q4.y*kreg[4*c4+1]
         + q4.z*kreg[4*c4+2] + q4.w*kreg[4*c4+3];
    }
    e = (gok && h < L) ? e : 0.0f;
    if (g == h) e = -INFINITY;
    ab[(size_t)h * WW * 128] = e;
  }
}

// ---------------------------------------------------------------------------
// energyW + softmax over [eH | eW].  grid (H, B), block 256.
// ---------------------------------------------------------------------------
__global__ __launch_bounds__(256) void energyW_softmax_kernel(
    const float* __restrict__ qt, const float* __restrict__ kt,
    float* __restrict__ att, const int* __restrict__ len_p)
{
  const int tid = threadIdx.x;
  const int h = blockIdx.x, b = blockIdx.y;
  int L = *len_p; L = L < 0 ? 0 : (L > 64 ? 64 : L);
  __shared__ float Qs[64][68];
  __shared__ float Ks[64][68];
  {
    const int c = tid & 63, wg2 = tid >> 6;
    const float* qb = qt + ((size_t)b * PP + (size_t)h * WW) * CQ + c;
    const float* kb = kt + ((size_t)b * PP + (size_t)h * WW) * CQ + c;
    #pragma unroll
    for (int r = 0; r < 16; ++r) {
      int w = wg2*16 + r;
      Qs[w][c] = qb[(size_t)w * CQ];
      Ks[w][c] = kb[(size_t)w * CQ];
    }
  }
  __syncthreads();
  const int g  = tid & 63;
  const int wg = tid >> 6;
  float kreg[64];
  #pragma unroll
  for (int c = 0; c < 64; ++c) kreg[c] = (c < L) ? Ks[g][c] : 0.0f;
  const bool gok = (g < L);
  float* ab = att + (((size_t)b * HH + h) * WW) * 128 + g;
  for (int r = 0; r < 16; ++r) {
    int w = wg*16 + r;
    float e = 0.0f;
    #pragma unroll
    for (int c4 = 0; c4 < 16; ++c4) {
      float4 q4 = *(const float4*)&Qs[w][4*c4];
      e += q4.x*kreg[4*c4+0] + q4.y*kreg[4*c4+1]
         + q4.z*kreg[4*c4+2] + q4.w*kreg[4*c4+3];
    }
    e = (gok && w < L) ? e : 0.0f;
    float eh = ab[(size_t)w * 128];
    float m = fmaxf(e, eh);
    #pragma unroll
    for (int d = 32; d > 0; d >>= 1) m = fmaxf(m, __shfl_xor(m, d, 64));
    float pe = __expf(e  - m);
    float ph = __expf(eh - m);
    float s = pe + ph;
    #pragma unroll
    for (int d = 32; d > 0; d >>= 1) s += __shfl_xor(s, d, 64);
    float inv = 1.0f / s;
    ab[(size_t)w * 128]      = ph * inv;   // attH
    ab[(size_t)w * 128 + 64] = pe * inv;   // attW
  }
}

// ---------------------------------------------------------------------------
// outH: per (b,w): oH[b,h,w,c] = sum_j att[b,h,w,j] * v_t[b, j*64+w, c]
// bf16 coalesced output (b,h,w,c). grid (W, B), block 256.
// ---------------------------------------------------------------------------
__global__ __launch_bounds__(256) void outH_kernel(
    const float* __restrict__ att, const __bf16* __restrict__ vt,
    __bf16* __restrict__ oH)
{
  const int tid = threadIdx.x;
  const int w = blockIdx.x, b = blockIdx.y;
  __shared__ float As[64][68];
  __shared__ float Bs[16][132];
  {
    int jf = tid & 15;
    int h0 = tid >> 4;
    const float* ab = att + (((size_t)b * HH) * WW + w) * 128;
    #pragma unroll
    for (int pp = 0; pp < 4; ++pp) {
      int hh2 = h0 + 16*pp;
      float4 v = *(const float4*)(ab + (size_t)hh2 * WW * 128 + 4*jf);
      *(float4*)&As[hh2][4*jf] = v;
    }
  }
  __syncthreads();
  const int tx = tid & 31;   // c' = 4*tx
  const int ty = tid >> 5;   // h = 8*ty + i
  const __bf16* vb = vt + ((size_t)b * PP + w) * CH;
  __bf16* ob = oH + ((size_t)b * HH * WW + w) * CH;   // + h*WW*CH + c
  for (int ct = 0; ct < 4; ++ct) {
    const int c0 = ct * 128;
    float4 acc[8];
    #pragma unroll
    for (int i = 0; i < 8; ++i) acc[i] = make_float4(0.f,0.f,0.f,0.f);
    for (int jt = 0; jt < 4; ++jt) {
      {
        int c4 = tid & 31;
        int jj = tid >> 5;
        #pragma unroll
        for (int pp = 0; pp < 2; ++pp) {
          int j = jj + 8*pp;
          bf16x4 v4 = *(const bf16x4*)(vb + (size_t)(jt*16 + j) * WW * CH + c0 + 4*c4);
          Bs[j][4*c4+0] = (float)v4[0];
          Bs[j][4*c4+1] = (float)v4[1];
          Bs[j][4*c4+2] = (float)v4[2];
          Bs[j][4*c4+3] = (float)v4[3];
        }
      }
      __syncthreads();
      #pragma unroll
      for (int kb = 0; kb < 4; ++kb) {
        float4 a4[8];
        #pragma unroll
        for (int i = 0; i < 8; ++i)
          a4[i] = *(const float4*)&As[8*ty+i][jt*16 + 4*kb];
        #pragma unroll
        for (int kk = 0; kk < 4; ++kk) {
          float4 b4 = *(const float4*)&Bs[4*kb+kk][4*tx];
          #pragma unroll
          for (int i = 0; i < 8; ++i) {
            float a = (kk==0)?a4[i].x:(kk==1)?a4[i].y:(kk==2)?a4[i].z:a4[i].w;
            acc[i].x += a * b4.x; acc[i].y += a * b4.y;
            acc[i].z += a * b4.z; acc[i].w += a * b4.w;
          }
        }
      }
      __syncthreads();
    }
    #pragma unroll
    for (int i = 0; i < 8; ++i) {
      int h = 8*ty + i;
      bf16x4 o4;
      o4[0] = (__bf16)acc[i].x; o4[1] = (__bf16)acc[i].y;
      o4[2] = (__bf16)acc[i].z; o4[3] = (__bf16)acc[i].w;
      *(bf16x4*)(ob + (size_t)h * WW * CH + c0 + 4*tx) = o4;
    }
  }
}

// ---------------------------------------------------------------------------
// outW + final: per (b,h): out = gamma*(outW + outH) + x1
// grid (H, B), block 256. Coalesced everywhere.
// ---------------------------------------------------------------------------
__global__ __launch_bounds__(256) void outW_final_kernel(
    const float* __restrict__ att, const __bf16* __restrict__ vt,
    const __bf16* __restrict__ oH,
    const float* __restrict__ x1, const float* __restrict__ gamma_p,
    float* __restrict__ out)
{
  const int tid = threadIdx.x;
  const int h = blockIdx.x, b = blockIdx.y;
  const float gamma = *gamma_p;
  __shared__ float As[64][68];
  __shared__ float Pool[64][132];
  {
    int jf = tid & 15;
    int w0 = tid >> 4;
    const float* ab = att + (((size_t)b * HH + h) * WW) * 128 + 64;
    #pragma unroll
    for (int pp = 0; pp < 4; ++pp) {
      int ww2 = w0 + 16*pp;
      float4 v = *(const float4*)(ab + (size_t)ww2 * 128 + 4*jf);
      *(float4*)&As[ww2][4*jf] = v;
    }
  }
  __syncthreads();
  const int tx = tid & 31;
  const int ty = tid >> 5;
  const __bf16* vb  = vt + ((size_t)b * PP + (size_t)h * WW) * CH;
  const __bf16* ohb = oH + ((size_t)b * HH * WW + (size_t)h * WW) * CH;
  for (int ct = 0; ct < 4; ++ct) {
    const int c0 = ct * 128;
    float4 acc[8];
    #pragma unroll
    for (int i = 0; i < 8; ++i) acc[i] = make_float4(0.f,0.f,0.f,0.f);
    for (int jt = 0; jt < 4; ++jt) {
      {
        int c4 = tid & 31;
        int jj = tid >> 5;
        #pragma unroll
        for (int pp = 0; pp < 2; ++pp) {
          int j = jj + 8*pp;
          bf16x4 v4 = *(const bf16x4*)(vb + (size_t)(jt*16 + j) * CH + c0 + 4*c4);
          Pool[j][4*c4+0] = (float)v4[0];
          Pool[j][4*c4+1] = (float)v4[1];
          Pool[j][4*c4+2] = (float)v4[2];
          Pool[j][4*c4+3] = (float)v4[3];
        }
      }
      __syncthreads();
      #pragma unroll
      for (int kb = 0; kb < 4; ++kb) {
        float4 a4[8];
        #pragma unroll
        for (int i = 0; i < 8; ++i)
          a4[i] = *(const float4*)&As[8*ty+i][jt*16 + 4*kb];
        #pragma unroll
        for (int kk = 0; kk < 4; ++kk) {
          float4 b4 = *(const float4*)&Pool[4*kb+kk][4*tx];
          #pragma unroll
          for (int i = 0; i < 8; ++i) {
            float a = (kk==0)?a4[i].x:(kk==1)?a4[i].y:(kk==2)?a4[i].z:a4[i].w;
            acc[i].x += a * b4.x; acc[i].y += a * b4.y;
            acc[i].z += a * b4.z; acc[i].w += a * b4.w;
          }
        }
      }
      __syncthreads();
    }
    // add outH (coalesced bf16 read) into acc, then transpose + final RMW
    #pragma unroll
    for (int i = 0; i < 8; ++i) {
      int w = 8*ty + i;
      bf16x4 o4 = *(const bf16x4*)(ohb + (size_t)w * CH + c0 + 4*tx);
      acc[i].x += (float)o4[0]; acc[i].y += (float)o4[1];
      acc[i].z += (float)o4[2]; acc[i].w += (float)o4[3];
    }
    #pragma unroll
    for (int i = 0; i < 8; ++i)
      *(float4*)&Pool[8*ty + i][4*tx] = acc[i];
    __syncthreads();
    {
      int wl = tid & 63;
      int cg = tid >> 6;
      const float* x1b = x1 + ((size_t)b * CH + c0) * PP + (size_t)h * WW + wl;
      float*       obp = out + ((size_t)b * CH + c0) * PP + (size_t)h * WW + wl;
      #pragma unroll
      for (int r = 0; r < 32; ++r) {
        int ci = cg*32 + r;
        obp[(size_t)ci * PP] = gamma * Pool[wl][ci] + x1b[(size_t)ci * PP];
      }
    }
    __syncthreads();
  }
}

// ---------------------------------------------------------------------------
extern "C" void kernel_launch(void* const* d_in, const int* in_sizes, int n_in,
                              void* d_out, int out_size, void* d_ws, size_t ws_size,
                              hipStream_t stream)
{
  const float* x1 = (const float*)d_in[0];
  const float* x2 = (const float*)d_in[1];
  const float* x3 = (const float*)d_in[2];
  const float* Wq = (const float*)d_in[3];
  const float* bq = (const float*)d_in[4];
  const float* Wk = (const float*)d_in[5];
  const float* bk = (const float*)d_in[6];
  const float* Wv = (const float*)d_in[7];
  const float* bv = (const float*)d_in[8];
  const float* gamma = (const float*)d_in[9];
  const int*   len   = (const int*)d_in[10];
  float* out = (float*)d_out;

  // workspace layout (96 MiB total, same footprint as R1):
  float*  q_t = (float*)d_ws;                        // (B,P,64)  f32  8 MiB
  float*  k_t = q_t + (size_t)BB * PP * CQ;          // (B,P,64)  f32  8 MiB
  float*  att = k_t + (size_t)BB * PP * CQ;          // (B,H,W,128) f32 16 MiB
  __bf16* v_t = (__bf16*)(att + (size_t)BB * PP * 128);  // (B,P,512) bf16 32 MiB
  __bf16* oH  = v_t + (size_t)BB * PP * CH;          // (B,H,W,512) bf16 32 MiB

  dim3 blk(256);
  proj_mfma_kernel<4,4,false,__bf16><<<dim3(BB*PP/128, CH/128), blk, 0, stream>>>(x3, Wv, bv, v_t, CH);
  proj_mfma_kernel<2,2,true ,float ><<<dim3(BB*PP/64,  1),      blk, 0, stream>>>(x1, Wq, bq, q_t, CQ);
  proj_mfma_kernel<2,2,true ,float ><<<dim3(BB*PP/64,  1),      blk, 0, stream>>>(x2, Wk, bk, k_t, CQ);
  energyH_kernel<<<dim3(WW, BB), blk, 0, stream>>>(q_t, k_t, att, len);
  energyW_softmax_kernel<<<dim3(HH, BB), blk, 0, stream>>>(q_t, k_t, att, len);
  outH_kernel<<<dim3(WW, BB), blk, 0, stream>>>(att, v_t, oH);
  outW_final_kernel<<<dim3(HH, BB), blk, 0, stream>>>(att, v_t, oH, x1, gamma, out);
}

// Round 4
// 204.758 us; speedup vs baseline: 4.8165x; 1.1940x over previous
//
#include <hip/hip_runtime.h>
#include <math.h>

#define CH 512
#define CQ 64
#define HH 64
#define WW 64
#define PP (HH*WW)   // 4096
#define BB 8

typedef __bf16 bf16x8 __attribute__((ext_vector_type(8)));
typedef __bf16 bf16x4 __attribute__((ext_vector_type(4)));
typedef float  f32x4  __attribute__((ext_vector_type(4)));

// ---- LDS helpers (inline asm; keep asm ds ops and compiler ds ops in
// ---- disjoint regions, one lgkmcnt(0)+sched_barrier(0) before MFMAs) ----
__device__ __forceinline__ unsigned lds_off(const void* p) {
  return (unsigned)(size_t)(__attribute__((address_space(3))) const void*)p;
}
__device__ __forceinline__ bf16x4 ds_tr16(unsigned addr) {
  bf16x4 r;
  asm volatile("ds_read_b64_tr_b16 %0, %1" : "=v"(r) : "v"(addr));
  return r;
}
__device__ __forceinline__ bf16x8 ds_b128(unsigned addr) {
  bf16x8 r;
  asm volatile("ds_read_b128 %0, %1" : "=v"(r) : "v"(addr));
  return r;
}

// ---------------------------------------------------------------------------
// proj_mfma: Y[m, o] = sum_c X[b, c, p] * W[o, c] + bias[o],  m = b*4096 + p
// bf16 MFMA 16x16x32, double-buffered LDS + register prefetch (1 barrier/step)
// SPLIT=true: hi+lo bf16 decomposition (3 MFMAs) for ~f32 accuracy.
// ---------------------------------------------------------------------------
template<int FM, int FN, bool SPLIT, typename OutT>
__global__ __launch_bounds__(256) void proj_mfma_kernel(
    const float* __restrict__ X, const float* __restrict__ W,
    const float* __restrict__ bias, OutT* __restrict__ Y, int Nout)
{
  constexpr int BM = 32 * FM;
  constexpr int BN = 32 * FN;
  constexpr int NS = SPLIT ? 2 : 1;
  constexpr int GA = BM / 64;   // A 8-elem load groups per thread per step
  constexpr int GB = BN / 64;
  __shared__ __align__(16) __bf16 As[2][NS][BM][40];
  __shared__ __align__(16) __bf16 Bs[2][NS][BN][40];

  const int tid = threadIdx.x;
  const int mblk = blockIdx.x * BM;
  const int nblk = blockIdx.y * BN;
  const int b     = mblk >> 12;
  const int pbase = mblk & 4095;
  const float* Xb = X + (size_t)b * CH * PP;

  const int l  = tid & 63;
  const int wv = tid >> 6;
  const int wr = wv >> 1, wc = wv & 1;
  const int lm = l & 15, lk = l >> 4;

  int ma[GA], ka[GA];
  #pragma unroll
  for (int gi = 0; gi < GA; ++gi) {
    int g = tid + gi * 256;
    ma[gi] = g % BM;
    ka[gi] = (g / BM) * 8;
  }
  int nb_[GB], kb_[GB];
  #pragma unroll
  for (int gi = 0; gi < GB; ++gi) {
    int g = tid + gi * 256;
    nb_[gi] = g >> 2;
    kb_[gi] = (g & 3) * 8;
  }

  float ra[GA][8], rb[GB][8];

  auto loadA = [&](int c0) {
    #pragma unroll
    for (int gi = 0; gi < GA; ++gi)
      #pragma unroll
      for (int jj = 0; jj < 8; ++jj)
        ra[gi][jj] = Xb[(size_t)(c0 + ka[gi] + jj) * PP + pbase + ma[gi]];
  };
  auto loadB = [&](int c0) {
    #pragma unroll
    for (int gi = 0; gi < GB; ++gi) {
      const float* src = W + (size_t)(nblk + nb_[gi]) * CH + c0 + kb_[gi];
      float4 f0 = *(const float4*)src;
      float4 f1 = *(const float4*)(src + 4);
      rb[gi][0]=f0.x; rb[gi][1]=f0.y; rb[gi][2]=f0.z; rb[gi][3]=f0.w;
      rb[gi][4]=f1.x; rb[gi][5]=f1.y; rb[gi][6]=f1.z; rb[gi][7]=f1.w;
    }
  };
  auto stage = [&](int par) {
    #pragma unroll
    for (int gi = 0; gi < GA; ++gi) {
      bf16x8 hv, lv;
      #pragma unroll
      for (int jj = 0; jj < 8; ++jj) {
        __bf16 hh = (__bf16)ra[gi][jj];
        hv[jj] = hh;
        if (SPLIT) lv[jj] = (__bf16)(ra[gi][jj] - (float)hh);
      }
      *(bf16x8*)&As[par][0][ma[gi]][ka[gi]] = hv;
      if (SPLIT) *(bf16x8*)&As[par][1][ma[gi]][ka[gi]] = lv;
    }
    #pragma unroll
    for (int gi = 0; gi < GB; ++gi) {
      bf16x8 hv, lv;
      #pragma unroll
      for (int jj = 0; jj < 8; ++jj) {
        __bf16 hh = (__bf16)rb[gi][jj];
        hv[jj] = hh;
        if (SPLIT) lv[jj] = (__bf16)(rb[gi][jj] - (float)hh);
      }
      *(bf16x8*)&Bs[par][0][nb_[gi]][kb_[gi]] = hv;
      if (SPLIT) *(bf16x8*)&Bs[par][1][nb_[gi]][kb_[gi]] = lv;
    }
  };

  f32x4 acc[FM][FN];
  #pragma unroll
  for (int j = 0; j < FN; ++j) {
    float bvj = bias[nblk + wc*FN*16 + j*16 + lm];
    #pragma unroll
    for (int i = 0; i < FM; ++i) {
      acc[i][j][0] = bvj; acc[i][j][1] = bvj;
      acc[i][j][2] = bvj; acc[i][j][3] = bvj;
    }
  }

  loadA(0); loadB(0);
  for (int t = 0; t < 16; ++t) {
    const int par = t & 1;
    stage(par);
    __syncthreads();
    if (t < 15) { loadA((t+1)*32); loadB((t+1)*32); }
    bf16x8 af[NS][FM], bfr[NS][FN];
    #pragma unroll
    for (int s = 0; s < NS; ++s) {
      #pragma unroll
      for (int i = 0; i < FM; ++i)
        af[s][i] = *(const bf16x8*)&As[par][s][wr*FM*16 + i*16 + lm][lk*8];
      #pragma unroll
      for (int j = 0; j < FN; ++j)
        bfr[s][j] = *(const bf16x8*)&Bs[par][s][wc*FN*16 + j*16 + lm][lk*8];
    }
    #pragma unroll
    for (int i = 0; i < FM; ++i) {
      #pragma unroll
      for (int j = 0; j < FN; ++j) {
        acc[i][j] = __builtin_amdgcn_mfma_f32_16x16x32_bf16(
            af[0][i], bfr[0][j], acc[i][j], 0, 0, 0);
        if (SPLIT) {
          acc[i][j] = __builtin_amdgcn_mfma_f32_16x16x32_bf16(
              af[0][i], bfr[1][j], acc[i][j], 0, 0, 0);
          acc[i][j] = __builtin_amdgcn_mfma_f32_16x16x32_bf16(
              af[1][i], bfr[0][j], acc[i][j], 0, 0, 0);
        }
      }
    }
  }
  #pragma unroll
  for (int i = 0; i < FM; ++i) {
    #pragma unroll
    for (int j = 0; j < FN; ++j) {
      #pragma unroll
      for (int r = 0; r < 4; ++r) {
        int mg = mblk + wr*FM*16 + i*16 + lk*4 + r;
        int ng = nblk + wc*FN*16 + j*16 + lm;
        Y[(size_t)mg * Nout + ng] = (OutT)acc[i][j][r];
      }
    }
  }
}

// ---------------------------------------------------------------------------
// energyH: att[b,h,w,g] = masked q.k with -inf diagonal. grid (W,B), 256.
// ---------------------------------------------------------------------------
__global__ __launch_bounds__(256) void energyH_kernel(
    const float* __restrict__ qt, const float* __restrict__ kt,
    float* __restrict__ att, const int* __restrict__ len_p)
{
  const int tid = threadIdx.x;
  const int w = blockIdx.x, b = blockIdx.y;
  int L = *len_p; L = L < 0 ? 0 : (L > 64 ? 64 : L);
  __shared__ float Qs[64][68];
  __shared__ float Ks[64][68];
  {
    const int c = tid & 63, hg = tid >> 6;
    const float* qb = qt + ((size_t)b * PP + w) * CQ + c;
    const float* kb = kt + ((size_t)b * PP + w) * CQ + c;
    #pragma unroll
    for (int r = 0; r < 16; ++r) {
      int h = hg*16 + r;
      Qs[h][c] = qb[(size_t)h * WW * CQ];
      Ks[h][c] = kb[(size_t)h * WW * CQ];
    }
  }
  __syncthreads();
  const int g  = tid & 63;
  const int wg = tid >> 6;
  float kreg[64];
  #pragma unroll
  for (int c = 0; c < 64; ++c) kreg[c] = (c < L) ? Ks[g][c] : 0.0f;
  const bool gok = (g < L);
  float* ab = att + (((size_t)b * HH) * WW + w) * 128 + g;
  for (int r = 0; r < 16; ++r) {
    int h = wg*16 + r;
    float e = 0.0f;
    #pragma unroll
    for (int c4 = 0; c4 < 16; ++c4) {
      float4 q4 = *(const float4*)&Qs[h][4*c4];
      e += q4.x*kreg[4*c4+0] + q4.y*kreg[4*c4+1]
         + q4.z*kreg[4*c4+2] + q4.w*kreg[4*c4+3];
    }
    e = (gok && h < L) ? e : 0.0f;
    if (g == h) e = -INFINITY;
    ab[(size_t)h * WW * 128] = e;
  }
}

// ---------------------------------------------------------------------------
// energyW + softmax over [eH | eW].  grid (H, B), block 256.
// ---------------------------------------------------------------------------
__global__ __launch_bounds__(256) void energyW_softmax_kernel(
    const float* __restrict__ qt, const float* __restrict__ kt,
    float* __restrict__ att, const int* __restrict__ len_p)
{
  const int tid = threadIdx.x;
  const int h = blockIdx.x, b = blockIdx.y;
  int L = *len_p; L = L < 0 ? 0 : (L > 64 ? 64 : L);
  __shared__ float Qs[64][68];
  __shared__ float Ks[64][68];
  {
    const int c = tid & 63, wg2 = tid >> 6;
    const float* qb = qt + ((size_t)b * PP + (size_t)h * WW) * CQ + c;
    const float* kb = kt + ((size_t)b * PP + (size_t)h * WW) * CQ + c;
    #pragma unroll
    for (int r = 0; r < 16; ++r) {
      int w = wg2*16 + r;
      Qs[w][c] = qb[(size_t)w * CQ];
      Ks[w][c] = kb[(size_t)w * CQ];
    }
  }
  __syncthreads();
  const int g  = tid & 63;
  const int wg = tid >> 6;
  float kreg[64];
  #pragma unroll
  for (int c = 0; c < 64; ++c) kreg[c] = (c < L) ? Ks[g][c] : 0.0f;
  const bool gok = (g < L);
  float* ab = att + (((size_t)b * HH + h) * WW) * 128 + g;
  for (int r = 0; r < 16; ++r) {
    int w = wg*16 + r;
    float e = 0.0f;
    #pragma unroll
    for (int c4 = 0; c4 < 16; ++c4) {
      float4 q4 = *(const float4*)&Qs[w][4*c4];
      e += q4.x*kreg[4*c4+0] + q4.y*kreg[4*c4+1]
         + q4.z*kreg[4*c4+2] + q4.w*kreg[4*c4+3];
    }
    e = (gok && w < L) ? e : 0.0f;
    float eh = ab[(size_t)w * 128];
    float m = fmaxf(e, eh);
    #pragma unroll
    for (int d = 32; d > 0; d >>= 1) m = fmaxf(m, __shfl_xor(m, d, 64));
    float pe = __expf(e  - m);
    float ph = __expf(eh - m);
    float s = pe + ph;
    #pragma unroll
    for (int d = 32; d > 0; d >>= 1) s += __shfl_xor(s, d, 64);
    float inv = 1.0f / s;
    ab[(size_t)w * 128]      = ph * inv;   // attH
    ab[(size_t)w * 128 + 64] = pe * inv;   // attW
  }
}

// ---------------------------------------------------------------------------
// V-tile staging into 16x16-subtiled LDS with j-permutation so that
// ds_read_b64_tr_b16 (lane addr = block_base + 8*l) yields B-fragments:
//   block (s,p): j = s*32 + 8*lk + 4*p + r  stored at row t = 4*lk + r
//   subtile element (j,c): off = ((s*2+p)*8 + (c>>4))*256 + t*16 + (c&15)
// ---------------------------------------------------------------------------
__device__ __forceinline__ int vsub_off(int j, int c0) {
  int s  = j >> 5;
  int p  = (j >> 2) & 1;
  int t  = ((j & 31) >> 3) * 4 + (j & 3);
  return ((s*2 + p)*8 + (c0 >> 4))*256 + t*16 + (c0 & 15);
}

// ---------------------------------------------------------------------------
// outH (MFMA): per (b,w): oH[b,h,w,c] = sum_j attH[h,j] * v[j*64+w, c]
// grid (W, B), block 256 (4 waves; wave wv owns h rows wv*16..+15).
// ---------------------------------------------------------------------------
__global__ __launch_bounds__(256) void outH_mfma_kernel(
    const float* __restrict__ att, const __bf16* __restrict__ vt,
    __bf16* __restrict__ oH)
{
  const int tid = threadIdx.x;
  const int w = blockIdx.x, b = blockIdx.y;
  const int l = tid & 63, wv = tid >> 6;
  const int lm = l & 15, lk = l >> 4;

  __shared__ __align__(16) __bf16 As[64][72];
  __shared__ __align__(16) __bf16 Bs[8192];

  // stage attH -> As bf16
  #pragma unroll
  for (int i = 0; i < 4; ++i) {
    int row  = i*16 + (tid >> 4);
    int jseg = tid & 15;
    float4 a4 = *(const float4*)(att + (((size_t)b*HH + row)*WW + w)*128 + jseg*4);
    bf16x4 h4;
    h4[0]=(__bf16)a4.x; h4[1]=(__bf16)a4.y; h4[2]=(__bf16)a4.z; h4[3]=(__bf16)a4.w;
    *(bf16x4*)&As[row][jseg*4] = h4;
  }

  const unsigned as_base = lds_off(&As[0][0]);
  const unsigned bs_base = lds_off(&Bs[0]);
  const __bf16* vb = vt + ((size_t)b * PP + w) * CH;
  __bf16* ob = oH + (((size_t)b * HH) * WW + w) * CH;

  for (int ct = 0; ct < 4; ++ct) {
    __syncthreads();   // Bs reuse + (first iter) As ready
    #pragma unroll
    for (int i = 0; i < 4; ++i) {
      int j  = i*16 + (tid >> 4);
      int c0 = (tid & 15) * 8;
      bf16x8 v8 = *(const bf16x8*)(vb + (size_t)j * WW * CH + ct*128 + c0);
      *(bf16x8*)&Bs[vsub_off(j, c0)] = v8;
    }
    __syncthreads();

    f32x4 acc[8];
    #pragma unroll
    for (int f = 0; f < 8; ++f) acc[f] = (f32x4){0.f,0.f,0.f,0.f};
    #pragma unroll
    for (int s = 0; s < 2; ++s) {
      bf16x8 af = ds_b128(as_base + (unsigned)(((wv*16+lm)*72 + s*32 + lk*8)*2));
      bf16x8 bf[8];
      #pragma unroll
      for (int f = 0; f < 8; ++f) {
        unsigned base = bs_base + (unsigned)(((s*2)*8 + f)*512) + (unsigned)(l*8);
        bf16x4 t0 = ds_tr16(base);
        bf16x4 t1 = ds_tr16(base + 8*512);   // p=1 block
        bf[f] = __builtin_shufflevector(t0, t1, 0,1,2,3,4,5,6,7);
      }
      asm volatile("s_waitcnt lgkmcnt(0)");
      __builtin_amdgcn_sched_barrier(0);
      #pragma unroll
      for (int f = 0; f < 8; ++f)
        acc[f] = __builtin_amdgcn_mfma_f32_16x16x32_bf16(af, bf[f], acc[f], 0,0,0);
    }
    // direct bf16 stores: 16-lane rows cover 32B contiguous chunks
    #pragma unroll
    for (int f = 0; f < 8; ++f) {
      #pragma unroll
      for (int r = 0; r < 4; ++r) {
        int h = wv*16 + lk*4 + r;
        ob[(size_t)h * WW * CH + ct*128 + f*16 + lm] = (__bf16)acc[f][r];
      }
    }
  }
}

// ---------------------------------------------------------------------------
// outW (MFMA) + final: per (b,h): out = gamma*(outW + oH) + x1
// grid (H, B), block 256.
// ---------------------------------------------------------------------------
__global__ __launch_bounds__(256) void outW_final_kernel(
    const float* __restrict__ att, const __bf16* __restrict__ vt,
    const __bf16* __restrict__ oH,
    const float* __restrict__ x1, const float* __restrict__ gamma_p,
    float* __restrict__ out)
{
  const int tid = threadIdx.x;
  const int h = blockIdx.x, b = blockIdx.y;
  const int l = tid & 63, wv = tid >> 6;
  const int lm = l & 15, lk = l >> 4;
  const float gamma = *gamma_p;

  __shared__ __align__(16) __bf16 As[64][72];
  __shared__ __align__(16) __bf16 Bs[8192];
  __shared__ float Sc[64][133];

  // stage attW -> As bf16
  #pragma unroll
  for (int i = 0; i < 4; ++i) {
    int row  = i*16 + (tid >> 4);
    int jseg = tid & 15;
    float4 a4 = *(const float4*)(att + (((size_t)b*HH + h)*WW + row)*128 + 64 + jseg*4);
    bf16x4 h4;
    h4[0]=(__bf16)a4.x; h4[1]=(__bf16)a4.y; h4[2]=(__bf16)a4.z; h4[3]=(__bf16)a4.w;
    *(bf16x4*)&As[row][jseg*4] = h4;
  }

  const unsigned as_base = lds_off(&As[0][0]);
  const unsigned bs_base = lds_off(&Bs[0]);
  const __bf16* vb  = vt + ((size_t)b * PP + (size_t)h * WW) * CH;
  const __bf16* ohb = oH + (((size_t)b * HH + h) * WW) * CH;

  for (int ct = 0; ct < 4; ++ct) {
    __syncthreads();
    #pragma unroll
    for (int i = 0; i < 4; ++i) {
      int j  = i*16 + (tid >> 4);
      int c0 = (tid & 15) * 8;
      bf16x8 v8 = *(const bf16x8*)(vb + (size_t)j * CH + ct*128 + c0);
      *(bf16x8*)&Bs[vsub_off(j, c0)] = v8;
    }
    __syncthreads();

    f32x4 acc[8];
    #pragma unroll
    for (int f = 0; f < 8; ++f) acc[f] = (f32x4){0.f,0.f,0.f,0.f};
    #pragma unroll
    for (int s = 0; s < 2; ++s) {
      bf16x8 af = ds_b128(as_base + (unsigned)(((wv*16+lm)*72 + s*32 + lk*8)*2));
      bf16x8 bf[8];
      #pragma unroll
      for (int f = 0; f < 8; ++f) {
        unsigned base = bs_base + (unsigned)(((s*2)*8 + f)*512) + (unsigned)(l*8);
        bf16x4 t0 = ds_tr16(base);
        bf16x4 t1 = ds_tr16(base + 8*512);
        bf[f] = __builtin_shufflevector(t0, t1, 0,1,2,3,4,5,6,7);
      }
      asm volatile("s_waitcnt lgkmcnt(0)");
      __builtin_amdgcn_sched_barrier(0);
      #pragma unroll
      for (int f = 0; f < 8; ++f)
        acc[f] = __builtin_amdgcn_mfma_f32_16x16x32_bf16(af, bf[f], acc[f], 0,0,0);
    }
    // acc -> Sc (w rows, chunk-local c cols)
    #pragma unroll
    for (int f = 0; f < 8; ++f) {
      #pragma unroll
      for (int r = 0; r < 4; ++r)
        Sc[wv*16 + lk*4 + r][f*16 + lm] = acc[f][r];
    }
    __syncthreads();
    // add oH (coalesced bf16x8 reads, LDS RMW)
    {
      int w_ = tid >> 2, cs = tid & 3;
      #pragma unroll
      for (int e = 0; e < 4; ++e) {
        bf16x8 o8 = *(const bf16x8*)(ohb + (size_t)w_ * CH + ct*128 + cs*32 + e*8);
        #pragma unroll
        for (int jj = 0; jj < 8; ++jj)
          Sc[w_][cs*32 + e*8 + jj] += (float)o8[jj];
      }
    }
    __syncthreads();
    // final: out = gamma*Sc + x1   (coalesced along w)
    {
      int wl = tid & 63, cg = tid >> 6;
      const float* x1b = x1 + ((size_t)b * CH + ct*128) * PP + (size_t)h * WW + wl;
      float*       obp = out + ((size_t)b * CH + ct*128) * PP + (size_t)h * WW + wl;
      #pragma unroll
      for (int r2 = 0; r2 < 32; ++r2) {
        int ci = cg*32 + r2;
        obp[(size_t)ci * PP] = gamma * Sc[wl][ci] + x1b[(size_t)ci * PP];
      }
    }
  }
}

// ---------------------------------------------------------------------------
extern "C" void kernel_launch(void* const* d_in, const int* in_sizes, int n_in,
                              void* d_out, int out_size, void* d_ws, size_t ws_size,
                              hipStream_t stream)
{
  const float* x1 = (const float*)d_in[0];
  const float* x2 = (const float*)d_in[1];
  const float* x3 = (const float*)d_in[2];
  const float* Wq = (const float*)d_in[3];
  const float* bq = (const float*)d_in[4];
  const float* Wk = (const float*)d_in[5];
  const float* bk = (const float*)d_in[6];
  const float* Wv = (const float*)d_in[7];
  const float* bv = (const float*)d_in[8];
  const float* gamma = (const float*)d_in[9];
  const int*   len   = (const int*)d_in[10];
  float* out = (float*)d_out;

  // workspace layout (96 MiB total):
  float*  q_t = (float*)d_ws;                            // (B,P,64)  f32   8 MiB
  float*  k_t = q_t + (size_t)BB * PP * CQ;              // (B,P,64)  f32   8 MiB
  float*  att = k_t + (size_t)BB * PP * CQ;              // (B,H,W,128) f32 16 MiB
  __bf16* v_t = (__bf16*)(att + (size_t)BB * PP * 128);  // (B,P,512) bf16 32 MiB
  __bf16* oH  = v_t + (size_t)BB * PP * CH;              // (B,H,W,512) bf16 32 MiB

  dim3 blk(256);
  proj_mfma_kernel<4,4,false,__bf16><<<dim3(BB*PP/128, CH/128), blk, 0, stream>>>(x3, Wv, bv, v_t, CH);
  proj_mfma_kernel<2,2,true ,float ><<<dim3(BB*PP/64,  1),      blk, 0, stream>>>(x1, Wq, bq, q_t, CQ);
  proj_mfma_kernel<2,2,true ,float ><<<dim3(BB*PP/64,  1),      blk, 0, stream>>>(x2, Wk, bk, k_t, CQ);
  energyH_kernel<<<dim3(WW, BB), blk, 0, stream>>>(q_t, k_t, att, len);
  energyW_softmax_kernel<<<dim3(HH, BB), blk, 0, stream>>>(q_t, k_t, att, len);
  outH_mfma_kernel<<<dim3(WW, BB), blk, 0, stream>>>(att, v_t, oH);
  outW_final_kernel<<<dim3(HH, BB), blk, 0, stream>>>(att, v_t, oH, x1, gamma, out);
}

// Round 5
// 174.980 us; speedup vs baseline: 5.6362x; 1.1702x over previous
//
#include <hip/hip_runtime.h>
#include <math.h>

#define CH 512
#define CQ 64
#define HH 64
#define WW 64
#define PP (HH*WW)   // 4096
#define BB 8

typedef __bf16 bf16x8 __attribute__((ext_vector_type(8)));
typedef __bf16 bf16x4 __attribute__((ext_vector_type(4)));
typedef float  f32x4  __attribute__((ext_vector_type(4)));

// ---- LDS helpers (inline asm; keep asm ds ops and compiler ds ops in
// ---- disjoint regions, one lgkmcnt(0)+sched_barrier(0) before MFMAs) ----
__device__ __forceinline__ unsigned lds_off(const void* p) {
  return (unsigned)(size_t)(__attribute__((address_space(3))) const void*)p;
}
__device__ __forceinline__ bf16x4 ds_tr16(unsigned addr) {
  bf16x4 r;
  asm volatile("ds_read_b64_tr_b16 %0, %1" : "=v"(r) : "v"(addr));
  return r;
}

// ---------------------------------------------------------------------------
// proj_mfma: Y[m, o] = sum_c X[b, c, p] * W[o, c] + bias[o],  m = b*4096 + p
// bf16 MFMA 16x16x32, double-buffered LDS + register prefetch (1 barrier/step)
// SPLIT=true: hi+lo bf16 decomposition (3 MFMAs) for ~f32 accuracy.
// ---------------------------------------------------------------------------
template<int FM, int FN, bool SPLIT, typename OutT>
__global__ __launch_bounds__(256) void proj_mfma_kernel(
    const float* __restrict__ X, const float* __restrict__ W,
    const float* __restrict__ bias, OutT* __restrict__ Y, int Nout)
{
  constexpr int BM = 32 * FM;
  constexpr int BN = 32 * FN;
  constexpr int NS = SPLIT ? 2 : 1;
  constexpr int GA = BM / 64;   // A 8-elem load groups per thread per step
  constexpr int GB = BN / 64;
  __shared__ __align__(16) __bf16 As[2][NS][BM][40];
  __shared__ __align__(16) __bf16 Bs[2][NS][BN][40];

  const int tid = threadIdx.x;
  const int mblk = blockIdx.x * BM;
  const int nblk = blockIdx.y * BN;
  const int b     = mblk >> 12;
  const int pbase = mblk & 4095;
  const float* Xb = X + (size_t)b * CH * PP;

  const int l  = tid & 63;
  const int wv = tid >> 6;
  const int wr = wv >> 1, wc = wv & 1;
  const int lm = l & 15, lk = l >> 4;

  int ma[GA], ka[GA];
  #pragma unroll
  for (int gi = 0; gi < GA; ++gi) {
    int g = tid + gi * 256;
    ma[gi] = g % BM;
    ka[gi] = (g / BM) * 8;
  }
  int nb_[GB], kb_[GB];
  #pragma unroll
  for (int gi = 0; gi < GB; ++gi) {
    int g = tid + gi * 256;
    nb_[gi] = g >> 2;
    kb_[gi] = (g & 3) * 8;
  }

  float ra[GA][8], rb[GB][8];

  auto loadA = [&](int c0) {
    #pragma unroll
    for (int gi = 0; gi < GA; ++gi)
      #pragma unroll
      for (int jj = 0; jj < 8; ++jj)
        ra[gi][jj] = Xb[(size_t)(c0 + ka[gi] + jj) * PP + pbase + ma[gi]];
  };
  auto loadB = [&](int c0) {
    #pragma unroll
    for (int gi = 0; gi < GB; ++gi) {
      const float* src = W + (size_t)(nblk + nb_[gi]) * CH + c0 + kb_[gi];
      float4 f0 = *(const float4*)src;
      float4 f1 = *(const float4*)(src + 4);
      rb[gi][0]=f0.x; rb[gi][1]=f0.y; rb[gi][2]=f0.z; rb[gi][3]=f0.w;
      rb[gi][4]=f1.x; rb[gi][5]=f1.y; rb[gi][6]=f1.z; rb[gi][7]=f1.w;
    }
  };
  auto stage = [&](int par) {
    #pragma unroll
    for (int gi = 0; gi < GA; ++gi) {
      bf16x8 hv, lv;
      #pragma unroll
      for (int jj = 0; jj < 8; ++jj) {
        __bf16 hh = (__bf16)ra[gi][jj];
        hv[jj] = hh;
        if (SPLIT) lv[jj] = (__bf16)(ra[gi][jj] - (float)hh);
      }
      *(bf16x8*)&As[par][0][ma[gi]][ka[gi]] = hv;
      if (SPLIT) *(bf16x8*)&As[par][1][ma[gi]][ka[gi]] = lv;
    }
    #pragma unroll
    for (int gi = 0; gi < GB; ++gi) {
      bf16x8 hv, lv;
      #pragma unroll
      for (int jj = 0; jj < 8; ++jj) {
        __bf16 hh = (__bf16)rb[gi][jj];
        hv[jj] = hh;
        if (SPLIT) lv[jj] = (__bf16)(rb[gi][jj] - (float)hh);
      }
      *(bf16x8*)&Bs[par][0][nb_[gi]][kb_[gi]] = hv;
      if (SPLIT) *(bf16x8*)&Bs[par][1][nb_[gi]][kb_[gi]] = lv;
    }
  };

  f32x4 acc[FM][FN];
  #pragma unroll
  for (int j = 0; j < FN; ++j) {
    float bvj = bias[nblk + wc*FN*16 + j*16 + lm];
    #pragma unroll
    for (int i = 0; i < FM; ++i) {
      acc[i][j][0] = bvj; acc[i][j][1] = bvj;
      acc[i][j][2] = bvj; acc[i][j][3] = bvj;
    }
  }

  loadA(0); loadB(0);
  for (int t = 0; t < 16; ++t) {
    const int par = t & 1;
    stage(par);
    __syncthreads();
    if (t < 15) { loadA((t+1)*32); loadB((t+1)*32); }
    bf16x8 af[NS][FM], bfr[NS][FN];
    #pragma unroll
    for (int s = 0; s < NS; ++s) {
      #pragma unroll
      for (int i = 0; i < FM; ++i)
        af[s][i] = *(const bf16x8*)&As[par][s][wr*FM*16 + i*16 + lm][lk*8];
      #pragma unroll
      for (int j = 0; j < FN; ++j)
        bfr[s][j] = *(const bf16x8*)&Bs[par][s][wc*FN*16 + j*16 + lm][lk*8];
    }
    #pragma unroll
    for (int i = 0; i < FM; ++i) {
      #pragma unroll
      for (int j = 0; j < FN; ++j) {
        acc[i][j] = __builtin_amdgcn_mfma_f32_16x16x32_bf16(
            af[0][i], bfr[0][j], acc[i][j], 0, 0, 0);
        if (SPLIT) {
          acc[i][j] = __builtin_amdgcn_mfma_f32_16x16x32_bf16(
              af[0][i], bfr[1][j], acc[i][j], 0, 0, 0);
          acc[i][j] = __builtin_amdgcn_mfma_f32_16x16x32_bf16(
              af[1][i], bfr[0][j], acc[i][j], 0, 0, 0);
        }
      }
    }
  }
  #pragma unroll
  for (int i = 0; i < FM; ++i) {
    #pragma unroll
    for (int j = 0; j < FN; ++j) {
      #pragma unroll
      for (int r = 0; r < 4; ++r) {
        int mg = mblk + wr*FM*16 + i*16 + lk*4 + r;
        int ng = nblk + wc*FN*16 + j*16 + lm;
        Y[(size_t)mg * Nout + ng] = (OutT)acc[i][j][r];
      }
    }
  }
}

// ---------------------------------------------------------------------------
// energyH: att[b,h,w,g] = masked q.k with -inf diagonal. grid (W,B), 256.
// ---------------------------------------------------------------------------
__global__ __launch_bounds__(256) void energyH_kernel(
    const float* __restrict__ qt, const float* __restrict__ kt,
    float* __restrict__ att, const int* __restrict__ len_p)
{
  const int tid = threadIdx.x;
  const int w = blockIdx.x, b = blockIdx.y;
  int L = *len_p; L = L < 0 ? 0 : (L > 64 ? 64 : L);
  __shared__ float Qs[64][68];
  __shared__ float Ks[64][68];
  {
    const int c = tid & 63, hg = tid >> 6;
    const float* qb = qt + ((size_t)b * PP + w) * CQ + c;
    const float* kb = kt + ((size_t)b * PP + w) * CQ + c;
    #pragma unroll
    for (int r = 0; r < 16; ++r) {
      int h = hg*16 + r;
      Qs[h][c] = qb[(size_t)h * WW * CQ];
      Ks[h][c] = kb[(size_t)h * WW * CQ];
    }
  }
  __syncthreads();
  const int g  = tid & 63;
  const int wg = tid >> 6;
  float kreg[64];
  #pragma unroll
  for (int c = 0; c < 64; ++c) kreg[c] = (c < L) ? Ks[g][c] : 0.0f;
  const bool gok = (g < L);
  float* ab = att + (((size_t)b * HH) * WW + w) * 128 + g;
  for (int r = 0; r < 16; ++r) {
    int h = wg*16 + r;
    float e = 0.0f;
    #pragma unroll
    for (int c4 = 0; c4 < 16; ++c4) {
      float4 q4 = *(const float4*)&Qs[h][4*c4];
      e += q4.x*kreg[4*c4+0] + q4.y*kreg[4*c4+1]
         + q4.z*kreg[4*c4+2] + q4.w*kreg[4*c4+3];
    }
    e = (gok && h < L) ? e : 0.0f;
    if (g == h) e = -INFINITY;
    ab[(size_t)h * WW * 128] = e;
  }
}

// ---------------------------------------------------------------------------
// energyW + softmax over [eH | eW].  grid (H, B), block 256.
// ---------------------------------------------------------------------------
__global__ __launch_bounds__(256) void energyW_softmax_kernel(
    const float* __restrict__ qt, const float* __restrict__ kt,
    float* __restrict__ att, const int* __restrict__ len_p)
{
  const int tid = threadIdx.x;
  const int h = blockIdx.x, b = blockIdx.y;
  int L = *len_p; L = L < 0 ? 0 : (L > 64 ? 64 : L);
  __shared__ float Qs[64][68];
  __shared__ float Ks[64][68];
  {
    const int c = tid & 63, wg2 = tid >> 6;
    const float* qb = qt + ((size_t)b * PP + (size_t)h * WW) * CQ + c;
    const float* kb = kt + ((size_t)b * PP + (size_t)h * WW) * CQ + c;
    #pragma unroll
    for (int r = 0; r < 16; ++r) {
      int w = wg2*16 + r;
      Qs[w][c] = qb[(size_t)w * CQ];
      Ks[w][c] = kb[(size_t)w * CQ];
    }
  }
  __syncthreads();
  const int g  = tid & 63;
  const int wg = tid >> 6;
  float kreg[64];
  #pragma unroll
  for (int c = 0; c < 64; ++c) kreg[c] = (c < L) ? Ks[g][c] : 0.0f;
  const bool gok = (g < L);
  float* ab = att + (((size_t)b * HH + h) * WW) * 128 + g;
  for (int r = 0; r < 16; ++r) {
    int w = wg*16 + r;
    float e = 0.0f;
    #pragma unroll
    for (int c4 = 0; c4 < 16; ++c4) {
      float4 q4 = *(const float4*)&Qs[w][4*c4];
      e += q4.x*kreg[4*c4+0] + q4.y*kreg[4*c4+1]
         + q4.z*kreg[4*c4+2] + q4.w*kreg[4*c4+3];
    }
    e = (gok && w < L) ? e : 0.0f;
    float eh = ab[(size_t)w * 128];
    float m = fmaxf(e, eh);
    #pragma unroll
    for (int d = 32; d > 0; d >>= 1) m = fmaxf(m, __shfl_xor(m, d, 64));
    float pe = __expf(e  - m);
    float ph = __expf(eh - m);
    float s = pe + ph;
    #pragma unroll
    for (int d = 32; d > 0; d >>= 1) s += __shfl_xor(s, d, 64);
    float inv = 1.0f / s;
    ab[(size_t)w * 128]      = ph * inv;   // attH
    ab[(size_t)w * 128 + 64] = pe * inv;   // attW
  }
}

// ---------------------------------------------------------------------------
// V-tile staging into 16x16-subtiled LDS with j-permutation so that
// ds_read_b64_tr_b16 (lane addr = block_base + 8*l) yields B-fragments:
//   block (s,p): j = s*32 + 8*lk + 4*p + r  stored at row t = 4*lk + r
//   subtile element (j,c): off = ((s*2+p)*8 + (c>>4))*256 + t*16 + (c&15)
// ---------------------------------------------------------------------------
__device__ __forceinline__ int vsub_off(int j, int c0) {
  int s  = j >> 5;
  int p  = (j >> 2) & 1;
  int t  = ((j & 31) >> 3) * 4 + (j & 3);
  return ((s*2 + p)*8 + (c0 >> 4))*256 + t*16 + (c0 & 15);
}

// ---------------------------------------------------------------------------
// outH (MFMA): per (b,w,ct): oH[b,h,w, ct*128+c'] = sum_j attH[h,j]*v[j*64+w,c]
// grid (W, 4, B), block 256 (4 waves; wave wv owns h rows wv*16..+15).
// A-fragments read directly from global att (f32->bf16 cvt), no As LDS.
// ---------------------------------------------------------------------------
__global__ __launch_bounds__(256) void outH_mfma_kernel(
    const float* __restrict__ att, const __bf16* __restrict__ vt,
    __bf16* __restrict__ oH)
{
  const int tid = threadIdx.x;
  const int w = blockIdx.x, ct = blockIdx.y, b = blockIdx.z;
  const int l = tid & 63, wv = tid >> 6;
  const int lm = l & 15, lk = l >> 4;

  __shared__ __align__(16) __bf16 Bs[8192];

  // stage V chunk (j rows strided WW*CH, c chunk ct*128)
  #pragma unroll
  for (int i = 0; i < 4; ++i) {
    int j  = i*16 + (tid >> 4);
    int c0 = (tid & 15) * 8;
    bf16x8 v8 = *(const bf16x8*)(vt + ((size_t)b*PP + (size_t)j*WW + w)*CH + ct*128 + c0);
    *(bf16x8*)&Bs[vsub_off(j, c0)] = v8;
  }

  // A fragments from global att (4 lk-lanes cover one 128B line per h-row)
  const int hrow = wv*16 + lm;
  const float* ab = att + (((size_t)b*HH + hrow)*WW + w)*128;
  bf16x8 af[2];
  #pragma unroll
  for (int s = 0; s < 2; ++s) {
    float4 a0 = *(const float4*)(ab + s*32 + lk*8);
    float4 a1 = *(const float4*)(ab + s*32 + lk*8 + 4);
    af[s][0]=(__bf16)a0.x; af[s][1]=(__bf16)a0.y; af[s][2]=(__bf16)a0.z; af[s][3]=(__bf16)a0.w;
    af[s][4]=(__bf16)a1.x; af[s][5]=(__bf16)a1.y; af[s][6]=(__bf16)a1.z; af[s][7]=(__bf16)a1.w;
  }
  __syncthreads();

  const unsigned bs_base = lds_off(&Bs[0]);
  f32x4 acc[8];
  #pragma unroll
  for (int f = 0; f < 8; ++f) acc[f] = (f32x4){0.f,0.f,0.f,0.f};
  #pragma unroll
  for (int s = 0; s < 2; ++s) {
    bf16x8 bfr[8];
    #pragma unroll
    for (int f = 0; f < 8; ++f) {
      unsigned base = bs_base + (unsigned)(((s*2)*8 + f)*512) + (unsigned)(l*8);
      bf16x4 t0 = ds_tr16(base);
      bf16x4 t1 = ds_tr16(base + 8*512);   // p=1 block
      bfr[f] = __builtin_shufflevector(t0, t1, 0,1,2,3,4,5,6,7);
    }
    asm volatile("s_waitcnt lgkmcnt(0)");
    __builtin_amdgcn_sched_barrier(0);
    #pragma unroll
    for (int f = 0; f < 8; ++f)
      acc[f] = __builtin_amdgcn_mfma_f32_16x16x32_bf16(af[s], bfr[f], acc[f], 0,0,0);
  }
  __bf16* ob = oH + (((size_t)b * HH) * WW + w) * CH + ct*128;
  #pragma unroll
  for (int f = 0; f < 8; ++f) {
    #pragma unroll
    for (int r = 0; r < 4; ++r) {
      int h = wv*16 + lk*4 + r;
      ob[(size_t)h * WW * CH + f*16 + lm] = (__bf16)acc[f][r];
    }
  }
}

// ---------------------------------------------------------------------------
// outW (MFMA) + final: per (b,h,ct): out = gamma*(outW + oH) + x1
// grid (H, 4, B), block 256. LDS union: Bs (16KB) then Sc halves (17.7KB).
// ---------------------------------------------------------------------------
__global__ __launch_bounds__(256) void outW_final_kernel(
    const float* __restrict__ att, const __bf16* __restrict__ vt,
    const __bf16* __restrict__ oH,
    const float* __restrict__ x1, const float* __restrict__ gamma_p,
    float* __restrict__ out)
{
  const int tid = threadIdx.x;
  const int h = blockIdx.x, ct = blockIdx.y, b = blockIdx.z;
  const int l = tid & 63, wv = tid >> 6;
  const int lm = l & 15, lk = l >> 4;
  const float gamma = *gamma_p;

  __shared__ __align__(16) char smem[64*69*4];   // 17664 B
  __bf16* Bs = (__bf16*)smem;                    // 8192 entries (16384 B)
  typedef float ScRow[69];
  ScRow* Sc = (ScRow*)smem;                      // [64][69] f32

  // stage V chunk (j rows contiguous)
  #pragma unroll
  for (int i = 0; i < 4; ++i) {
    int j  = i*16 + (tid >> 4);
    int c0 = (tid & 15) * 8;
    bf16x8 v8 = *(const bf16x8*)(vt + ((size_t)b*PP + (size_t)h*WW + j)*CH + ct*128 + c0);
    *(bf16x8*)&Bs[vsub_off(j, c0)] = v8;
  }

  // A fragments (attW) from global
  const int wrow = wv*16 + lm;
  const float* ab = att + (((size_t)b*HH + h)*WW + wrow)*128 + 64;
  bf16x8 af[2];
  #pragma unroll
  for (int s = 0; s < 2; ++s) {
    float4 a0 = *(const float4*)(ab + s*32 + lk*8);
    float4 a1 = *(const float4*)(ab + s*32 + lk*8 + 4);
    af[s][0]=(__bf16)a0.x; af[s][1]=(__bf16)a0.y; af[s][2]=(__bf16)a0.z; af[s][3]=(__bf16)a0.w;
    af[s][4]=(__bf16)a1.x; af[s][5]=(__bf16)a1.y; af[s][6]=(__bf16)a1.z; af[s][7]=(__bf16)a1.w;
  }
  __syncthreads();

  const unsigned bs_base = lds_off(&Bs[0]);
  f32x4 acc[8];
  #pragma unroll
  for (int f = 0; f < 8; ++f) acc[f] = (f32x4){0.f,0.f,0.f,0.f};
  #pragma unroll
  for (int s = 0; s < 2; ++s) {
    bf16x8 bfr[8];
    #pragma unroll
    for (int f = 0; f < 8; ++f) {
      unsigned base = bs_base + (unsigned)(((s*2)*8 + f)*512) + (unsigned)(l*8);
      bf16x4 t0 = ds_tr16(base);
      bf16x4 t1 = ds_tr16(base + 8*512);
      bfr[f] = __builtin_shufflevector(t0, t1, 0,1,2,3,4,5,6,7);
    }
    asm volatile("s_waitcnt lgkmcnt(0)");
    __builtin_amdgcn_sched_barrier(0);
    #pragma unroll
    for (int f = 0; f < 8; ++f)
      acc[f] = __builtin_amdgcn_mfma_f32_16x16x32_bf16(af[s], bfr[f], acc[f], 0,0,0);
  }

  const __bf16* ohb = oH + (((size_t)b*HH + h) * WW) * CH + ct*128;
  #pragma unroll
  for (int hf = 0; hf < 2; ++hf) {
    __syncthreads();   // Bs->Sc reuse (hf=0) / prev-half Sc reads done (hf=1)
    // acc -> Sc (w rows, half-local c cols)
    #pragma unroll
    for (int f2 = 0; f2 < 4; ++f2) {
      int f = hf*4 + f2;
      #pragma unroll
      for (int r = 0; r < 4; ++r)
        Sc[wv*16 + lk*4 + r][f2*16 + lm] = acc[f][r];
    }
    __syncthreads();
    // add oH (coalesced bf16x8 reads, LDS RMW; 2-way banks = free)
    {
      int w_ = tid >> 2, q = tid & 3;
      #pragma unroll
      for (int e = 0; e < 2; ++e) {
        int cl = q*16 + e*8;
        bf16x8 o8 = *(const bf16x8*)(ohb + (size_t)w_ * CH + hf*64 + cl);
        #pragma unroll
        for (int jj = 0; jj < 8; ++jj)
          Sc[w_][cl + jj] += (float)o8[jj];
      }
    }
    __syncthreads();
    // final: out = gamma*Sc + x1   (coalesced along w; transposed Sc read)
    {
      int wl = tid & 63, cg = tid >> 6;
      const float* x1b = x1 + ((size_t)b*CH + ct*128 + hf*64)*PP + (size_t)h*WW + wl;
      float*       obp = out + ((size_t)b*CH + ct*128 + hf*64)*PP + (size_t)h*WW + wl;
      #pragma unroll
      for (int r2 = 0; r2 < 16; ++r2) {
        int ci = cg*16 + r2;
        obp[(size_t)ci * PP] = gamma * Sc[wl][ci] + x1b[(size_t)ci * PP];
      }
    }
  }
}

// ---------------------------------------------------------------------------
extern "C" void kernel_launch(void* const* d_in, const int* in_sizes, int n_in,
                              void* d_out, int out_size, void* d_ws, size_t ws_size,
                              hipStream_t stream)
{
  const float* x1 = (const float*)d_in[0];
  const float* x2 = (const float*)d_in[1];
  const float* x3 = (const float*)d_in[2];
  const float* Wq = (const float*)d_in[3];
  const float* bq = (const float*)d_in[4];
  const float* Wk = (const float*)d_in[5];
  const float* bk = (const float*)d_in[6];
  const float* Wv = (const float*)d_in[7];
  const float* bv = (const float*)d_in[8];
  const float* gamma = (const float*)d_in[9];
  const int*   len   = (const int*)d_in[10];
  float* out = (float*)d_out;

  // workspace layout (96 MiB total):
  float*  q_t = (float*)d_ws;                            // (B,P,64)  f32   8 MiB
  float*  k_t = q_t + (size_t)BB * PP * CQ;              // (B,P,64)  f32   8 MiB
  float*  att = k_t + (size_t)BB * PP * CQ;              // (B,H,W,128) f32 16 MiB
  __bf16* v_t = (__bf16*)(att + (size_t)BB * PP * 128);  // (B,P,512) bf16 32 MiB
  __bf16* oH  = v_t + (size_t)BB * PP * CH;              // (B,H,W,512) bf16 32 MiB

  dim3 blk(256);
  proj_mfma_kernel<4,4,false,__bf16><<<dim3(BB*PP/128, CH/128), blk, 0, stream>>>(x3, Wv, bv, v_t, CH);
  proj_mfma_kernel<2,2,true ,float ><<<dim3(BB*PP/64,  1),      blk, 0, stream>>>(x1, Wq, bq, q_t, CQ);
  proj_mfma_kernel<2,2,true ,float ><<<dim3(BB*PP/64,  1),      blk, 0, stream>>>(x2, Wk, bk, k_t, CQ);
  energyH_kernel<<<dim3(WW, BB), blk, 0, stream>>>(q_t, k_t, att, len);
  energyW_softmax_kernel<<<dim3(HH, BB), blk, 0, stream>>>(q_t, k_t, att, len);
  outH_mfma_kernel<<<dim3(WW, 4, BB), blk, 0, stream>>>(att, v_t, oH);
  outW_final_kernel<<<dim3(HH, 4, BB), blk, 0, stream>>>(att, v_t, oH, x1, gamma, out);
}